// Round 8
// baseline (233.038 us; speedup 1.0000x reference)
//
#include <hip/hip_runtime.h>
#include <hip/hip_bf16.h>
#include <stdint.h>

#define LAG 5
#define NROW 4096
#define NREG 500
#define NTGT 500
#define O_REAL 8000     /* HH*NTGT */
#define KP 2560         /* padded K = 40*64  (real K = 2500) */
#define BK 64
#define NT 40           /* K-tiles */

#define NBLK_A 10240    /* NROW*(KP/4)/256 */
#define NBLK_B 15625    /* O_REAL*NREG/256 */
#define NBLK_P 949      /* ceil((O_REAL*15 + 192*(KP/4))/256) */

#define MT 32           /* M-tiles of 128 */
#define NTL 63          /* N-tiles of 128 (8064 cols >= 8000) */

typedef __bf16 bf16x8 __attribute__((ext_vector_type(8)));
typedef float f32x4 __attribute__((ext_vector_type(4)));

__device__ __forceinline__ unsigned short f2bf(float f) {
  unsigned u = __float_as_uint(f);
  return (unsigned short)((u + 0x7fffu + ((u >> 16) & 1u)) >> 16);
}

__device__ __forceinline__ void async16(void* lds_base, const void* g) {
  __builtin_amdgcn_global_load_lds(
      (const __attribute__((address_space(1))) unsigned int*)g,
      (__attribute__((address_space(3))) unsigned int*)lds_base,
      16, 0, 0);
}

// ---- merged prep: convA [0,NBLK_A) | convB [NBLK_A,NBLK_A+NBLK_B) | padB [rest) ----------------
__global__ __launch_bounds__(256) void convAll(const float* __restrict__ AX,
                                               const float* __restrict__ W0,
                                               unsigned short* __restrict__ Ab,
                                               unsigned short* __restrict__ Bb) {
  int b = blockIdx.x;
  if (b < NBLK_A) {
    int idx = b * 256 + threadIdx.x;
    int n = idx / (KP / 4);
    int c4 = idx - n * (KP / 4);
    int k = c4 * 4;
    ushort4 o;
    if (k < LAG * NREG) {
      int l = k / NREG, r = k - l * NREG;
      float4 v = *(const float4*)(AX + ((size_t)l * NROW + n) * NREG + r);
      o.x = f2bf(v.x); o.y = f2bf(v.y); o.z = f2bf(v.z); o.w = f2bf(v.w);
    } else {
      o.x = 0; o.y = 0; o.z = 0; o.w = 0;
    }
    *(ushort4*)(Ab + (size_t)idx * 4) = o;
  } else if (b < NBLK_A + NBLK_B) {
    int idx = (b - NBLK_A) * 256 + threadIdx.x;
    int o = idx / NREG, r = idx - o * NREG;
    const float* s = W0 + (size_t)idx * LAG;
    #pragma unroll
    for (int j = 0; j < LAG; ++j)
      Bb[(size_t)o * KP + (size_t)(LAG - 1 - j) * NREG + r] = f2bf(s[j]);
  } else {
    int idx = (b - NBLK_A - NBLK_B) * 256 + threadIdx.x;    // ushort4 units
    const int A4 = O_REAL * 15;                             // 60 pad elems/row
    ushort4 z; z.x = 0; z.y = 0; z.z = 0; z.w = 0;
    if (idx < A4) {
      int row = idx / 15, c4 = idx - row * 15;
      *(ushort4*)(Bb + (size_t)row * KP + 2500 + c4 * 4) = z;
    } else {
      int j = idx - A4;
      if (j < 192 * (KP / 4))
        *(ushort4*)(Bb + (size_t)O_REAL * KP + (size_t)j * 4) = z;
    }
  }
}

// ---------------- 128x128 8-phase bf16 GEMM + fused MLP tail, 2 blocks/CU -----------------------
// v7: v4's verified 8-phase schedule transplanted to a 128x128 tile / 4-wave / 64 KiB-LDS block so
// TWO blocks co-reside per CU — cross-block wave overlap fills the barrier/lgkm stalls that
// serialize reads and MFMA in the 1-resident 256x256 config (m114/m103 mechanism).
// Per wave: 64x64 output, acc[4][4]; 8 MFMA/phase; reads 8/4/4/0 per buffer; 1 STG (2 loads)/phase.
// Hazards (same proof as v4): buf.B reads retire ph2/ph6-END; buf.A retire ph3/ph7-END; each STG
// lands >= 1 full barrier after its buffer's reads retire. Gates: 12 outstanding, vmcnt(4) drains
// the 8 composing the next tile (B staged 4 phases earlier + A staged 2 phases earlier).
__global__ __launch_bounds__(256, 2) void gemm8(const unsigned short* __restrict__ A,
                                                const unsigned short* __restrict__ B,
                                                const float* __restrict__ b0,
                                                const float* __restrict__ W1g,
                                                const float* __restrict__ b1g,
                                                const float* __restrict__ W2g,
                                                const float* __restrict__ b2g,
                                                float* __restrict__ out) {
  extern __shared__ char smem[];
  char* sAc = smem;            // [2][16384]
  char* sBc = smem + 32768;    // [2][16384]

  int bid = blockIdx.x;
  int swz = (bid & 7) * (MT * NTL / 8) + (bid >> 3);   // XCD-aware, bijective (2016 % 8 == 0)
  int mt = swz & 31, ntile = swz >> 5;                 // 32 M-tiles x 63 N-tiles (M fast)
  int row0 = mt * 128, col0 = ntile * 128;

  int tid = threadIdx.x, l = tid & 63, w = tid >> 6;   // 4 waves
  int wr = w >> 1, wc = w & 1;                         // 2x2 wave grid, 64x64 per wave

  // staging source pointers (pre-swizzled global source, linear LDS dest)
  int sr = l >> 3;                 // row within 8-row chunk
  int ss = (l & 7) ^ sr;           // swizzled 16B slot
  const unsigned short* gApre0 = A + (size_t)(row0 + (w * 2 + 0) * 8 + sr) * KP + ss * 8;
  const unsigned short* gApre1 = A + (size_t)(row0 + (w * 2 + 1) * 8 + sr) * KP + ss * 8;
  const unsigned short* gBpre0 = B + (size_t)(col0 + (w * 2 + 0) * 8 + sr) * KP + ss * 8;
  const unsigned short* gBpre1 = B + (size_t)(col0 + (w * 2 + 1) * 8 + sr) * KP + ss * 8;

#define STG_A(buf, half, t) do { \
    async16(sAc + (buf) * 16384 + (half) * 8192 + (w * 2 + 0) * 1024, gApre0 + (size_t)(half) * 64 * KP + (size_t)(t) * BK); \
    async16(sAc + (buf) * 16384 + (half) * 8192 + (w * 2 + 1) * 1024, gApre1 + (size_t)(half) * 64 * KP + (size_t)(t) * BK); \
  } while (0)
#define STG_B(buf, half, t) do { \
    async16(sBc + (buf) * 16384 + (half) * 8192 + (w * 2 + 0) * 1024, gBpre0 + (size_t)(half) * 64 * KP + (size_t)(t) * BK); \
    async16(sBc + (buf) * 16384 + (half) * 8192 + (w * 2 + 1) * 1024, gBpre1 + (size_t)(half) * 64 * KP + (size_t)(t) * BK); \
  } while (0)

  // fragment read offsets (row stride 128 B; row&7 == l&7 for all fragment rows)
  int arowb = (wr * 64 + (l & 15)) * 128;      // byte offset of A row
  int browb = (wc * 64 + (l & 15)) * 128;      // byte offset of B row
  int c0 = (((l >> 4) << 4)) ^ ((l & 7) << 4); // kk=0 swizzled col byte; kk=1 -> ^64

  auto lda = [&](int buf, int mi, int kk) -> bf16x8 {
    return *(const bf16x8*)(sAc + buf * 16384 + arowb + mi * 2048 + (c0 ^ (kk * 64)));
  };
  auto ldb = [&](int buf, int ni, int kk) -> bf16x8 {
    return *(const bf16x8*)(sBc + buf * 16384 + browb + ni * 2048 + (c0 ^ (kk * 64)));
  };

  f32x4 acc[4][4];
  #pragma unroll
  for (int i = 0; i < 4; ++i)
    #pragma unroll
    for (int j = 0; j < 4; ++j) acc[i][j] = (f32x4){0.f, 0.f, 0.f, 0.f};

#define PH_SYNC() do { __builtin_amdgcn_s_barrier(); \
    asm volatile("s_waitcnt lgkmcnt(0)" ::: "memory"); \
    __builtin_amdgcn_s_setprio(1); } while (0)
#define PH_END() do { __builtin_amdgcn_s_setprio(0); __builtin_amdgcn_s_barrier(); } while (0)

// 8 MFMA: 2 mi x 2 ni x 2 kk into acc[MOFF..MOFF+1][NIOFF..NIOFF+1]
#define MFMA_Q(MOFF, AF, NIOFF) do { \
    _Pragma("unroll") \
    for (int mi = 0; mi < 2; ++mi) { \
      _Pragma("unroll") \
      for (int ni = 0; ni < 2; ++ni) { \
        acc[(MOFF) + mi][(NIOFF) + ni] = __builtin_amdgcn_mfma_f32_16x16x32_bf16(AF[mi][0], bb[(NIOFF) + ni][0], acc[(MOFF) + mi][(NIOFF) + ni], 0, 0, 0); \
        acc[(MOFF) + mi][(NIOFF) + ni] = __builtin_amdgcn_mfma_f32_16x16x32_bf16(AF[mi][1], bb[(NIOFF) + ni][1], acc[(MOFF) + mi][(NIOFF) + ni], 0, 0, 0); \
      } \
    } \
  } while (0)

  // prologue: T0 full {B,A} + T1.B -> 12 loads/thread; gate T0 (T1.B's 4 in flight)
  STG_B(0, 0, 0); STG_B(0, 1, 0); STG_A(0, 0, 0); STG_A(0, 1, 0);
  STG_B(1, 0, 1); STG_B(1, 1, 1);
  asm volatile("s_waitcnt vmcnt(4)" ::: "memory");
  __builtin_amdgcn_s_barrier();

  for (int t = 0; t < NT; t += 2) {
    const bool last = (t == NT - 2);
    bf16x8 a01[2][2], a23[2][2], bb[4][2];

    // ---- ph1: read bb01 + a01 (buf0, 8R); stage A(t+1)->buf1.h0
    #pragma unroll
    for (int ni = 0; ni < 2; ++ni) { bb[ni][0] = ldb(0, ni, 0); bb[ni][1] = ldb(0, ni, 1); }
    #pragma unroll
    for (int mi = 0; mi < 2; ++mi) { a01[mi][0] = lda(0, mi, 0); a01[mi][1] = lda(0, mi, 1); }
    STG_A(1, 0, t + 1);
    PH_SYNC(); MFMA_Q(0, a01, 0); PH_END();

    // ---- ph2: read bb23 (4R); stage A(t+1)->buf1.h1
    #pragma unroll
    for (int ni = 2; ni < 4; ++ni) { bb[ni][0] = ldb(0, ni, 0); bb[ni][1] = ldb(0, ni, 1); }
    STG_A(1, 1, t + 1);
    PH_SYNC(); MFMA_Q(0, a01, 2); PH_END();

    // ---- ph3: read a23 (4R); stage B(t+2)->buf0.h0 (buf0.B reads retired ph2-END)
    #pragma unroll
    for (int mi = 0; mi < 2; ++mi) { a23[mi][0] = lda(0, 2 + mi, 0); a23[mi][1] = lda(0, 2 + mi, 1); }
    if (!last) STG_B(0, 0, t + 2);
    PH_SYNC(); MFMA_Q(2, a23, 0); PH_END();

    // ---- ph4: stage B(t+2)->buf0.h1; GATE tile t+1 (12 outstanding, drain B(t+1)+A(t+1))
    if (!last) STG_B(0, 1, t + 2);
    if (last) asm volatile("s_waitcnt vmcnt(0)" ::: "memory");
    else      asm volatile("s_waitcnt vmcnt(4)" ::: "memory");
    __builtin_amdgcn_s_barrier();
    asm volatile("s_waitcnt lgkmcnt(0)" ::: "memory");
    __builtin_amdgcn_s_setprio(1);
    MFMA_Q(2, a23, 2);
    PH_END();

    // ---- ph5: read bb01 + a01 (buf1, 8R); stage A(t+2)->buf0.h0 (buf0.A reads retired ph3-END)
    #pragma unroll
    for (int ni = 0; ni < 2; ++ni) { bb[ni][0] = ldb(1, ni, 0); bb[ni][1] = ldb(1, ni, 1); }
    #pragma unroll
    for (int mi = 0; mi < 2; ++mi) { a01[mi][0] = lda(1, mi, 0); a01[mi][1] = lda(1, mi, 1); }
    if (!last) STG_A(0, 0, t + 2);
    PH_SYNC(); MFMA_Q(0, a01, 0); PH_END();

    // ---- ph6: read bb23 (buf1, 4R); stage A(t+2)->buf0.h1
    #pragma unroll
    for (int ni = 2; ni < 4; ++ni) { bb[ni][0] = ldb(1, ni, 0); bb[ni][1] = ldb(1, ni, 1); }
    if (!last) STG_A(0, 1, t + 2);
    PH_SYNC(); MFMA_Q(0, a01, 2); PH_END();

    // ---- ph7: read a23 (buf1, 4R); stage B(t+3)->buf1.h0 (buf1.B reads retired ph6-END)
    #pragma unroll
    for (int mi = 0; mi < 2; ++mi) { a23[mi][0] = lda(1, 2 + mi, 0); a23[mi][1] = lda(1, 2 + mi, 1); }
    if (!last) STG_B(1, 0, t + 3);
    PH_SYNC(); MFMA_Q(2, a23, 0); PH_END();

    // ---- ph8: stage B(t+3)->buf1.h1; GATE tile t+2 (12 outstanding, drain B(t+2)+A(t+2))
    if (!last) STG_B(1, 1, t + 3);
    if (last) asm volatile("s_waitcnt vmcnt(0)" ::: "memory");
    else      asm volatile("s_waitcnt vmcnt(4)" ::: "memory");
    __builtin_amdgcn_s_barrier();
    asm volatile("s_waitcnt lgkmcnt(0)" ::: "memory");
    __builtin_amdgcn_s_setprio(1);
    MFMA_Q(2, a23, 2);
    __builtin_amdgcn_s_setprio(0);
    __builtin_amdgcn_s_barrier();
  }

  // ================= fused epilogue (round-2 structure, 128-tile geometry) =================
  // Step 1: 4 waves dump acc into 128x128 bf16 X tile (32 KiB, row stride 256 B). acc dies here.
  int lq = l >> 4, lr = l & 15;
  int t0v = col0 >> 4;                     // first of this block's 8 targets

  float bias[4];
  #pragma unroll
  for (int ni = 0; ni < 4; ++ni) {
    int gcol = col0 + wc * 64 + ni * 16 + lr;
    bias[ni] = (gcol < O_REAL) ? b0[gcol] : 0.f;
  }

  #pragma unroll
  for (int mi = 0; mi < 4; ++mi) {
    #pragma unroll
    for (int ni = 0; ni < 4; ++ni) {
      #pragma unroll
      for (int r = 0; r < 4; ++r) {
        int rowL = wr * 64 + mi * 16 + lq * 4 + r;
        int colL = wc * 64 + ni * 16 + lr;
        int sw = ((rowL ^ (rowL >> 2)) & 7) << 4;
        float v = fmaxf(acc[mi][ni][r] + bias[ni], 0.f);
        *(unsigned short*)(smem + (size_t)rowL * 256 + ((colL * 2) ^ sw)) = f2bf(v);
      }
    }
  }
  __syncthreads();

  // Step 2: wave w owns targets 2w, 2w+1; lanes = rows (2 row-groups of 64).
  int uw = __builtin_amdgcn_readfirstlane(w);
  float oacc[2][2];
  #pragma unroll
  for (int g = 0; g < 2; ++g) {
    int tloc = uw * 2 + g;
    int tt = t0v + tloc;
    bool tvalid = (tt < NTGT);
    const float* w1t = W1g + (size_t)tt * 256;
    float b1v[16], w2v[16];
    float b2v = 0.f;
    if (tvalid) {
      #pragma unroll
      for (int e4 = 0; e4 < 4; ++e4) {
        float4 ba = *(const float4*)(b1g + (size_t)tt * 16 + e4 * 4);
        float4 wa = *(const float4*)(W2g + (size_t)tt * 16 + e4 * 4);
        b1v[e4 * 4 + 0] = ba.x; b1v[e4 * 4 + 1] = ba.y; b1v[e4 * 4 + 2] = ba.z; b1v[e4 * 4 + 3] = ba.w;
        w2v[e4 * 4 + 0] = wa.x; w2v[e4 * 4 + 1] = wa.y; w2v[e4 * 4 + 2] = wa.z; w2v[e4 * 4 + 3] = wa.w;
      }
      b2v = b2g[tt];
    }
    #pragma unroll
    for (int rg = 0; rg < 2; ++rg) {
      int rowL = rg * 64 + l;
      int sw = ((rowL ^ (rowL >> 2)) & 7) << 4;
      const char* bp = smem + (size_t)rowL * 256;
      uint4 va = *(const uint4*)(bp + ((tloc * 32) ^ sw));
      uint4 vb = *(const uint4*)(bp + ((tloc * 32 + 16) ^ sw));
      unsigned q0 = va.x, q1 = va.y, q2 = va.z, q3 = va.w;
      unsigned q4 = vb.x, q5 = vb.y, q6 = vb.z, q7 = vb.w;
      float x[16];
      x[0]  = __uint_as_float(q0 << 16); x[1]  = __uint_as_float(q0 & 0xffff0000u);
      x[2]  = __uint_as_float(q1 << 16); x[3]  = __uint_as_float(q1 & 0xffff0000u);
      x[4]  = __uint_as_float(q2 << 16); x[5]  = __uint_as_float(q2 & 0xffff0000u);
      x[6]  = __uint_as_float(q3 << 16); x[7]  = __uint_as_float(q3 & 0xffff0000u);
      x[8]  = __uint_as_float(q4 << 16); x[9]  = __uint_as_float(q4 & 0xffff0000u);
      x[10] = __uint_as_float(q5 << 16); x[11] = __uint_as_float(q5 & 0xffff0000u);
      x[12] = __uint_as_float(q6 << 16); x[13] = __uint_as_float(q6 & 0xffff0000u);
      x[14] = __uint_as_float(q7 << 16); x[15] = __uint_as_float(q7 & 0xffff0000u);
      float o = 0.f;
      if (tvalid) {
        #pragma unroll
        for (int e = 0; e < 16; ++e) {
          float4 wq0 = *(const float4*)(w1t + e * 16 + 0);
          float4 wq1 = *(const float4*)(w1t + e * 16 + 4);
          float4 wq2 = *(const float4*)(w1t + e * 16 + 8);
          float4 wq3 = *(const float4*)(w1t + e * 16 + 12);
          float s = b1v[e];
          s = fmaf(x[0],  wq0.x, s); s = fmaf(x[1],  wq0.y, s);
          s = fmaf(x[2],  wq0.z, s); s = fmaf(x[3],  wq0.w, s);
          s = fmaf(x[4],  wq1.x, s); s = fmaf(x[5],  wq1.y, s);
          s = fmaf(x[6],  wq1.z, s); s = fmaf(x[7],  wq1.w, s);
          s = fmaf(x[8],  wq2.x, s); s = fmaf(x[9],  wq2.y, s);
          s = fmaf(x[10], wq2.z, s); s = fmaf(x[11], wq2.w, s);
          s = fmaf(x[12], wq3.x, s); s = fmaf(x[13], wq3.y, s);
          s = fmaf(x[14], wq3.z, s); s = fmaf(x[15], wq3.w, s);
          s = fmaxf(s, 0.f);
          o = fmaf(s, w2v[e], o);
        }
        o += b2v;
      }
      oacc[g][rg] = o;
    }
  }
  __syncthreads();   // everyone done reading X

  // Step 3: transpose o through LDS ([128][9] f32 = 4.6 KB over dead X), coalesced out stores
  {
    float* sOut = (float*)smem;
    #pragma unroll
    for (int g = 0; g < 2; ++g) {
      int tloc = uw * 2 + g;
      #pragma unroll
      for (int rg = 0; rg < 2; ++rg)
        sOut[(rg * 64 + l) * 9 + tloc] = oacc[g][rg];
    }
    __syncthreads();
    int c = tid & 7, rr = tid >> 3;       // 8 targets x 32 row-slots
    bool cv = (t0v + c < NTGT);
    #pragma unroll
    for (int j = 0; j < 4; ++j) {
      int row = rr + 32 * j;
      if (cv) out[(size_t)(row0 + row) * NTGT + (t0v + c)] = sOut[row * 9 + c];
    }
  }
#undef STG_A
#undef STG_B
#undef PH_SYNC
#undef PH_END
#undef MFMA_Q
}

extern "C" void kernel_launch(void* const* d_in, const int* in_sizes, int n_in,
                              void* d_out, int out_size, void* d_ws, size_t ws_size,
                              hipStream_t stream) {
  const float* AX = (const float*)d_in[0];
  const float* W0 = (const float*)d_in[1];
  const float* b0 = (const float*)d_in[2];
  const float* W1 = (const float*)d_in[3];
  const float* b1 = (const float*)d_in[4];
  const float* W2 = (const float*)d_in[5];
  const float* b2 = (const float*)d_in[6];
  float* out = (float*)d_out;

  char* ws = (char*)d_ws;
  const size_t szA = (size_t)NROW * KP * 2;     // 20.97 MB
  unsigned short* Ab = (unsigned short*)ws;
  unsigned short* Bb = (unsigned short*)(ws + szA);   // [8192][2560] bf16 = 41.9 MB

  hipFuncSetAttribute((const void*)gemm8, hipFuncAttributeMaxDynamicSharedMemorySize, 65536);

  convAll<<<NBLK_A + NBLK_B + NBLK_P, 256, 0, stream>>>(AX, W0, Ab, Bb);
  gemm8<<<MT * NTL, 256, 65536, stream>>>(Ab, Bb, b0, W1, b1, W2, b2, out);
}

// Round 9
// 213.591 us; speedup vs baseline: 1.0910x; 1.0910x over previous
//
#include <hip/hip_runtime.h>
#include <hip/hip_bf16.h>
#include <stdint.h>

#define LAG 5
#define NROW 4096
#define NREG 500
#define NTGT 500
#define O_REAL 8000     /* HH*NTGT */
#define KP 2560         /* padded K = 40*64  (real K = 2500) */
#define NPAD 8192       /* GEMM N extent = 32*256 (cols >= 8000 masked) */
#define BK 64
#define NT 40           /* K-tiles */

#define NBLK_A 10240    /* NROW*(KP/4)/256 */
#define NBLK_B 15625    /* O_REAL*NREG/256 */
#define NBLK_P 949      /* ceil((O_REAL*15 + 192*(KP/4))/256) */

typedef __bf16 bf16x8 __attribute__((ext_vector_type(8)));
typedef float f32x4 __attribute__((ext_vector_type(4)));

__device__ __forceinline__ unsigned short f2bf(float f) {
  unsigned u = __float_as_uint(f);
  return (unsigned short)((u + 0x7fffu + ((u >> 16) & 1u)) >> 16);
}

__device__ __forceinline__ void async16(void* lds_base, const void* g) {
  __builtin_amdgcn_global_load_lds(
      (const __attribute__((address_space(1))) unsigned int*)g,
      (__attribute__((address_space(3))) unsigned int*)lds_base,
      16, 0, 0);
}

// ---- merged prep: convA [0,NBLK_A) | convB [NBLK_A,NBLK_A+NBLK_B) | padB [rest) ----------------
__global__ __launch_bounds__(256) void convAll(const float* __restrict__ AX,
                                               const float* __restrict__ W0,
                                               unsigned short* __restrict__ Ab,
                                               unsigned short* __restrict__ Bb) {
  int b = blockIdx.x;
  if (b < NBLK_A) {
    int idx = b * 256 + threadIdx.x;
    int n = idx / (KP / 4);
    int c4 = idx - n * (KP / 4);
    int k = c4 * 4;
    ushort4 o;
    if (k < LAG * NREG) {
      int l = k / NREG, r = k - l * NREG;
      float4 v = *(const float4*)(AX + ((size_t)l * NROW + n) * NREG + r);
      o.x = f2bf(v.x); o.y = f2bf(v.y); o.z = f2bf(v.z); o.w = f2bf(v.w);
    } else {
      o.x = 0; o.y = 0; o.z = 0; o.w = 0;
    }
    *(ushort4*)(Ab + (size_t)idx * 4) = o;
  } else if (b < NBLK_A + NBLK_B) {
    int idx = (b - NBLK_A) * 256 + threadIdx.x;
    int o = idx / NREG, r = idx - o * NREG;
    const float* s = W0 + (size_t)idx * LAG;
    #pragma unroll
    for (int j = 0; j < LAG; ++j)
      Bb[(size_t)o * KP + (size_t)(LAG - 1 - j) * NREG + r] = f2bf(s[j]);
  } else {
    int idx = (b - NBLK_A - NBLK_B) * 256 + threadIdx.x;    // ushort4 units
    const int A4 = O_REAL * 15;                             // 60 pad elems/row
    ushort4 z; z.x = 0; z.y = 0; z.z = 0; z.w = 0;
    if (idx < A4) {
      int row = idx / 15, c4 = idx - row * 15;
      *(ushort4*)(Bb + (size_t)row * KP + 2500 + c4 * 4) = z;
    } else {
      int j = idx - A4;
      if (j < 192 * (KP / 4))
        *(ushort4*)(Bb + (size_t)O_REAL * KP + (size_t)j * 4) = z;
    }
  }
}

// ---------------- 256x256 8-phase bf16 GEMM + fused MLP tail ------------------------------------
// K-loop v8: READ-AHEAD pipeline. Each phase issues the NEXT phase's fragments; consume waits are
// COUNTED lgkm (not 0) so the LDS pipe processes reads underneath the previous phase's MFMA
// section instead of serializing behind lgkmcnt(0). Read issue per phase: 4/8/0/12.
//   ph1: issue bb23(b0); lgkm(4);  a03xbb01      ph5: issue bb23(b1); lgkm(4);  a03xbb01
//   ph2: issue a47(b0);  lgkm(8);  a03xbb23      ph6: issue a47(b1);  lgkm(8);  a03xbb23
//   ph3: (0R);           lgkm(0);  a47xbb01      ph7: (0R);           lgkm(0);  a47xbb01
//   ph4: gate vmcnt(4); issue bb01+a03(b1) 12R; no-wait; a47xbb23     ph8: sym (b0, t+2)
// Slot liveness (all WAR >= 1 barrier apart): a03 w:ph4/ph8 r:ph5-6/ph1-2; a47 w:ph2/ph6 r:ph3-4/
// ph7-8; bb01 w:ph4/ph8 r:ph5,ph7/ph1,ph3; bb23 w:ph1/ph5 r:ph2,ph4/ph6,ph8.
// Staging/gates identical to verified r7: STG ph1-8 = A(t+1)h0,h1,B(t+2)h0,h1,A(t+2)h0,h1,
// B(t+3)h0,h1; gates vmcnt(4) at ph4/ph8; buf reads only after their gate.
__global__ __launch_bounds__(512, 2) void gemm8(const unsigned short* __restrict__ A,
                                                const unsigned short* __restrict__ B,
                                                const float* __restrict__ b0,
                                                const float* __restrict__ W1g,
                                                const float* __restrict__ b1g,
                                                const float* __restrict__ W2g,
                                                const float* __restrict__ b2g,
                                                float* __restrict__ out) {
  extern __shared__ char smem[];
  char* sAc = smem;            // [2][32768]
  char* sBc = smem + 65536;    // [2][32768]

  int bid = blockIdx.x;
  int swz = (bid & 7) * 64 + (bid >> 3);       // XCD-aware, bijective (512 % 8 == 0)
  int mt = swz & 15, ntile = swz >> 4;         // 16 M-tiles x 32 N-tiles
  int row0 = mt * 256, col0 = ntile * 256;

  int tid = threadIdx.x, l = tid & 63, w = tid >> 6;
  int wr = w >> 2, wc = w & 3;

  // staging source pointers (pre-swizzled global source, linear LDS dest)
  int sr = l >> 3;                 // row within 8-row chunk
  int ss = (l & 7) ^ sr;           // swizzled 16B slot
  const unsigned short* gApre0 = A + (size_t)(row0 + (w * 2 + 0) * 8 + sr) * KP + ss * 8;
  const unsigned short* gApre1 = A + (size_t)(row0 + (w * 2 + 1) * 8 + sr) * KP + ss * 8;
  const unsigned short* gBpre0 = B + (size_t)(col0 + (w * 2 + 0) * 8 + sr) * KP + ss * 8;
  const unsigned short* gBpre1 = B + (size_t)(col0 + (w * 2 + 1) * 8 + sr) * KP + ss * 8;

#define STG_A(buf, half, t) do { \
    async16(sAc + (buf) * 32768 + (half) * 16384 + (w * 2 + 0) * 1024, gApre0 + (size_t)(half) * 128 * KP + (size_t)(t) * BK); \
    async16(sAc + (buf) * 32768 + (half) * 16384 + (w * 2 + 1) * 1024, gApre1 + (size_t)(half) * 128 * KP + (size_t)(t) * BK); \
  } while (0)
#define STG_B(buf, half, t) do { \
    async16(sBc + (buf) * 32768 + (half) * 16384 + (w * 2 + 0) * 1024, gBpre0 + (size_t)(half) * 128 * KP + (size_t)(t) * BK); \
    async16(sBc + (buf) * 32768 + (half) * 16384 + (w * 2 + 1) * 1024, gBpre1 + (size_t)(half) * 128 * KP + (size_t)(t) * BK); \
  } while (0)

  // fragment read offsets (row&7 == l&7 for all fragment rows)
  int arowb = (wr * 128 + (l & 15)) * 128;     // byte offset of A row
  int browb = (wc * 64 + (l & 15)) * 128;      // byte offset of B row
  int c0 = (((l >> 4) << 4)) ^ ((l & 7) << 4); // kk=0 swizzled col byte; kk=1 -> ^64

  auto lda = [&](int buf, int mi, int kk) -> bf16x8 {
    return *(const bf16x8*)(sAc + buf * 32768 + arowb + mi * 2048 + (c0 ^ (kk * 64)));
  };
  auto ldb = [&](int buf, int ni, int kk) -> bf16x8 {
    return *(const bf16x8*)(sBc + buf * 32768 + browb + ni * 2048 + (c0 ^ (kk * 64)));
  };

  f32x4 acc[8][4];
  #pragma unroll
  for (int i = 0; i < 8; ++i)
    #pragma unroll
    for (int j = 0; j < 4; ++j) acc[i][j] = (f32x4){0.f, 0.f, 0.f, 0.f};

#define MFMA_Q(MOFF, AF, NIOFF) do { \
    _Pragma("unroll") \
    for (int mi = 0; mi < 4; ++mi) { \
      _Pragma("unroll") \
      for (int ni = 0; ni < 2; ++ni) { \
        acc[(MOFF) + mi][(NIOFF) + ni] = __builtin_amdgcn_mfma_f32_16x16x32_bf16(AF[mi][0], bb[(NIOFF) + ni][0], acc[(MOFF) + mi][(NIOFF) + ni], 0, 0, 0); \
        acc[(MOFF) + mi][(NIOFF) + ni] = __builtin_amdgcn_mfma_f32_16x16x32_bf16(AF[mi][1], bb[(NIOFF) + ni][1], acc[(MOFF) + mi][(NIOFF) + ni], 0, 0, 0); \
      } \
    } \
  } while (0)

  // prologue: T0 full {B,A} + T1.B -> 12 loads/thread; gate T0 (T1.B's 4 in flight)
  STG_B(0, 0, 0); STG_B(0, 1, 0); STG_A(0, 0, 0); STG_A(0, 1, 0);
  STG_B(1, 0, 1); STG_B(1, 1, 1);
  asm volatile("s_waitcnt vmcnt(4)" ::: "memory");
  __builtin_amdgcn_s_barrier();

  // loop-carried fragment slots
  bf16x8 a03[4][2], a47[4][2], bb[4][2];
  // prologue reads (the "ph8-equivalent" 12R): bb01 + a03 of buf0
  #pragma unroll
  for (int ni = 0; ni < 2; ++ni) { bb[ni][0] = ldb(0, ni, 0); bb[ni][1] = ldb(0, ni, 1); }
  #pragma unroll
  for (int mi = 0; mi < 4; ++mi) { a03[mi][0] = lda(0, mi, 0); a03[mi][1] = lda(0, mi, 1); }

  for (int t = 0; t < NT; t += 2) {
    const bool last = (t == NT - 2);

    // ---- ph1: issue bb23(buf0) [4R]; STG A(t+1)h0; wait prev-12 (keep 4 flying); a03 x bb01
    #pragma unroll
    for (int ni = 2; ni < 4; ++ni) { bb[ni][0] = ldb(0, ni, 0); bb[ni][1] = ldb(0, ni, 1); }
    STG_A(1, 0, t + 1);
    __builtin_amdgcn_s_barrier();
    asm volatile("s_waitcnt lgkmcnt(4)" ::: "memory");
    __builtin_amdgcn_s_setprio(1);
    MFMA_Q(0, a03, 0);
    __builtin_amdgcn_s_setprio(0);
    __builtin_amdgcn_s_barrier();

    // ---- ph2: issue a47(buf0) [8R]; STG A(t+1)h1; wait bb23 (keep 8 flying); a03 x bb23
    #pragma unroll
    for (int mi = 0; mi < 4; ++mi) { a47[mi][0] = lda(0, 4 + mi, 0); a47[mi][1] = lda(0, 4 + mi, 1); }
    STG_A(1, 1, t + 1);
    __builtin_amdgcn_s_barrier();
    asm volatile("s_waitcnt lgkmcnt(8)" ::: "memory");
    __builtin_amdgcn_s_setprio(1);
    MFMA_Q(0, a03, 2);
    __builtin_amdgcn_s_setprio(0);
    __builtin_amdgcn_s_barrier();

    // ---- ph3: 0R; STG B(t+2)h0; wait a47 (cheap: had ph2's MFMA span); a47 x bb01
    if (!last) STG_B(0, 0, t + 2);
    __builtin_amdgcn_s_barrier();
    asm volatile("s_waitcnt lgkmcnt(0)" ::: "memory");
    __builtin_amdgcn_s_setprio(1);
    MFMA_Q(4, a47, 0);
    __builtin_amdgcn_s_setprio(0);
    __builtin_amdgcn_s_barrier();

    // ---- ph4: STG B(t+2)h1; GATE vmcnt(4) [A(t+1)+B(t+1) landed]; post-gate issue
    //           bb01+a03(buf1) [12R] (processed under this MFMA); no lgkm wait; a47 x bb23
    if (!last) STG_B(0, 1, t + 2);
    if (last) asm volatile("s_waitcnt vmcnt(0)" ::: "memory");
    else      asm volatile("s_waitcnt vmcnt(4)" ::: "memory");
    __builtin_amdgcn_s_barrier();
    #pragma unroll
    for (int ni = 0; ni < 2; ++ni) { bb[ni][0] = ldb(1, ni, 0); bb[ni][1] = ldb(1, ni, 1); }
    #pragma unroll
    for (int mi = 0; mi < 4; ++mi) { a03[mi][0] = lda(1, mi, 0); a03[mi][1] = lda(1, mi, 1); }
    __builtin_amdgcn_s_setprio(1);
    MFMA_Q(4, a47, 2);
    __builtin_amdgcn_s_setprio(0);
    __builtin_amdgcn_s_barrier();

    // ---- ph5: issue bb23(buf1) [4R]; STG A(t+2)h0; wait ph4's 12 (keep 4); a03 x bb01
    #pragma unroll
    for (int ni = 2; ni < 4; ++ni) { bb[ni][0] = ldb(1, ni, 0); bb[ni][1] = ldb(1, ni, 1); }
    if (!last) STG_A(0, 0, t + 2);
    __builtin_amdgcn_s_barrier();
    asm volatile("s_waitcnt lgkmcnt(4)" ::: "memory");
    __builtin_amdgcn_s_setprio(1);
    MFMA_Q(0, a03, 0);
    __builtin_amdgcn_s_setprio(0);
    __builtin_amdgcn_s_barrier();

    // ---- ph6: issue a47(buf1) [8R]; STG A(t+2)h1; wait bb23 (keep 8); a03 x bb23
    #pragma unroll
    for (int mi = 0; mi < 4; ++mi) { a47[mi][0] = lda(1, 4 + mi, 0); a47[mi][1] = lda(1, 4 + mi, 1); }
    if (!last) STG_A(0, 1, t + 2);
    __builtin_amdgcn_s_barrier();
    asm volatile("s_waitcnt lgkmcnt(8)" ::: "memory");
    __builtin_amdgcn_s_setprio(1);
    MFMA_Q(0, a03, 2);
    __builtin_amdgcn_s_setprio(0);
    __builtin_amdgcn_s_barrier();

    // ---- ph7: 0R; STG B(t+3)h0; wait a47; a47 x bb01
    if (!last) STG_B(1, 0, t + 3);
    __builtin_amdgcn_s_barrier();
    asm volatile("s_waitcnt lgkmcnt(0)" ::: "memory");
    __builtin_amdgcn_s_setprio(1);
    MFMA_Q(4, a47, 0);
    __builtin_amdgcn_s_setprio(0);
    __builtin_amdgcn_s_barrier();

    // ---- ph8: STG B(t+3)h1; GATE vmcnt(4) [B(t+2)+A(t+2) landed]; post-gate issue
    //           bb01+a03(buf0, t+2) [12R]; no lgkm wait; a47 x bb23
    if (!last) STG_B(1, 1, t + 3);
    if (last) asm volatile("s_waitcnt vmcnt(0)" ::: "memory");
    else      asm volatile("s_waitcnt vmcnt(4)" ::: "memory");
    __builtin_amdgcn_s_barrier();
    if (!last) {
      #pragma unroll
      for (int ni = 0; ni < 2; ++ni) { bb[ni][0] = ldb(0, ni, 0); bb[ni][1] = ldb(0, ni, 1); }
      #pragma unroll
      for (int mi = 0; mi < 4; ++mi) { a03[mi][0] = lda(0, mi, 0); a03[mi][1] = lda(0, mi, 1); }
    }
    __builtin_amdgcn_s_setprio(1);
    MFMA_Q(4, a47, 2);
    __builtin_amdgcn_s_setprio(0);
    __builtin_amdgcn_s_barrier();
  }

  // ================= epilogue (byte-identical to verified round-2/round-4) =================
  // Step 1: ALL waves dump acc into full 256x256 bf16 X tile (exactly 128 KiB). acc dies here.
  int lq = l >> 4, lr = l & 15;
  int t0 = col0 >> 4;                      // first of this block's 16 targets

  float bias[4];
  #pragma unroll
  for (int ni = 0; ni < 4; ++ni) {
    int gcol = col0 + wc * 64 + ni * 16 + lr;
    bias[ni] = (gcol < O_REAL) ? b0[gcol] : 0.f;
  }

  __syncthreads();
  #pragma unroll
  for (int mi = 0; mi < 8; ++mi) {
    #pragma unroll
    for (int ni = 0; ni < 4; ++ni) {
      #pragma unroll
      for (int r = 0; r < 4; ++r) {
        int rowL = wr * 128 + mi * 16 + lq * 4 + r;
        int colL = wc * 64 + ni * 16 + lr;
        int sw = ((rowL ^ (rowL >> 2)) & 7) << 4;
        float v = fmaxf(acc[mi][ni][r] + bias[ni], 0.f);
        *(unsigned short*)(smem + (size_t)rowL * 512 + ((colL * 2) ^ sw)) = f2bf(v);
      }
    }
  }
  __syncthreads();

  // Step 2: wave w owns targets 2w, 2w+1; lanes = rows. W via wave-uniform (scalar) loads.
  int uw = __builtin_amdgcn_readfirstlane(w);
  float oacc[2][4];
  #pragma unroll
  for (int g = 0; g < 2; ++g) {
    int tloc = uw * 2 + g;
    int tt = t0 + tloc;
    bool tvalid = (tt < NTGT);
    const float* w1t = W1g + (size_t)tt * 256;
    float b1v[16], w2v[16];
    float b2v = 0.f;
    if (tvalid) {
      #pragma unroll
      for (int e4 = 0; e4 < 4; ++e4) {
        float4 ba = *(const float4*)(b1g + (size_t)tt * 16 + e4 * 4);
        float4 wa = *(const float4*)(W2g + (size_t)tt * 16 + e4 * 4);
        b1v[e4 * 4 + 0] = ba.x; b1v[e4 * 4 + 1] = ba.y; b1v[e4 * 4 + 2] = ba.z; b1v[e4 * 4 + 3] = ba.w;
        w2v[e4 * 4 + 0] = wa.x; w2v[e4 * 4 + 1] = wa.y; w2v[e4 * 4 + 2] = wa.z; w2v[e4 * 4 + 3] = wa.w;
      }
      b2v = b2g[tt];
    }
    #pragma unroll
    for (int rg = 0; rg < 4; ++rg) {
      int rowL = rg * 64 + l;
      int sw = ((rowL ^ (rowL >> 2)) & 7) << 4;
      const char* bp = smem + (size_t)rowL * 512;
      uint4 va = *(const uint4*)(bp + ((tloc * 32) ^ sw));
      uint4 vb = *(const uint4*)(bp + ((tloc * 32 + 16) ^ sw));
      unsigned q0 = va.x, q1 = va.y, q2 = va.z, q3 = va.w;
      unsigned q4 = vb.x, q5 = vb.y, q6 = vb.z, q7 = vb.w;
      float x[16];
      x[0]  = __uint_as_float(q0 << 16); x[1]  = __uint_as_float(q0 & 0xffff0000u);
      x[2]  = __uint_as_float(q1 << 16); x[3]  = __uint_as_float(q1 & 0xffff0000u);
      x[4]  = __uint_as_float(q2 << 16); x[5]  = __uint_as_float(q2 & 0xffff0000u);
      x[6]  = __uint_as_float(q3 << 16); x[7]  = __uint_as_float(q3 & 0xffff0000u);
      x[8]  = __uint_as_float(q4 << 16); x[9]  = __uint_as_float(q4 & 0xffff0000u);
      x[10] = __uint_as_float(q5 << 16); x[11] = __uint_as_float(q5 & 0xffff0000u);
      x[12] = __uint_as_float(q6 << 16); x[13] = __uint_as_float(q6 & 0xffff0000u);
      x[14] = __uint_as_float(q7 << 16); x[15] = __uint_as_float(q7 & 0xffff0000u);
      float o = 0.f;
      if (tvalid) {
        #pragma unroll
        for (int e = 0; e < 16; ++e) {
          float4 wq0 = *(const float4*)(w1t + e * 16 + 0);
          float4 wq1 = *(const float4*)(w1t + e * 16 + 4);
          float4 wq2 = *(const float4*)(w1t + e * 16 + 8);
          float4 wq3 = *(const float4*)(w1t + e * 16 + 12);
          float s = b1v[e];
          s = fmaf(x[0],  wq0.x, s); s = fmaf(x[1],  wq0.y, s);
          s = fmaf(x[2],  wq0.z, s); s = fmaf(x[3],  wq0.w, s);
          s = fmaf(x[4],  wq1.x, s); s = fmaf(x[5],  wq1.y, s);
          s = fmaf(x[6],  wq1.z, s); s = fmaf(x[7],  wq1.w, s);
          s = fmaf(x[8],  wq2.x, s); s = fmaf(x[9],  wq2.y, s);
          s = fmaf(x[10], wq2.z, s); s = fmaf(x[11], wq2.w, s);
          s = fmaf(x[12], wq3.x, s); s = fmaf(x[13], wq3.y, s);
          s = fmaf(x[14], wq3.z, s); s = fmaf(x[15], wq3.w, s);
          s = fmaxf(s, 0.f);
          o = fmaf(s, w2v[e], o);
        }
        o += b2v;
      }
      oacc[g][rg] = o;
    }
  }
  __syncthreads();   // everyone done reading X

  // Step 3: transpose o through LDS ([256][17] f32 = 17.4 KB over dead X), coalesced out stores
  {
    float* sOut = (float*)smem;
    #pragma unroll
    for (int g = 0; g < 2; ++g) {
      int tloc = uw * 2 + g;
      #pragma unroll
      for (int rg = 0; rg < 4; ++rg)
        sOut[(rg * 64 + l) * 17 + tloc] = oacc[g][rg];
    }
    __syncthreads();
    int c = tid & 15, rr = tid >> 4;
    bool cv = (t0 + c < NTGT);
    #pragma unroll
    for (int j = 0; j < 8; ++j) {
      int row = rr + 32 * j;
      if (cv) out[(size_t)(row0 + row) * NTGT + (t0 + c)] = sOut[row * 17 + c];
    }
  }
#undef STG_A
#undef STG_B
#undef MFMA_Q
}

extern "C" void kernel_launch(void* const* d_in, const int* in_sizes, int n_in,
                              void* d_out, int out_size, void* d_ws, size_t ws_size,
                              hipStream_t stream) {
  const float* AX = (const float*)d_in[0];
  const float* W0 = (const float*)d_in[1];
  const float* b0 = (const float*)d_in[2];
  const float* W1 = (const float*)d_in[3];
  const float* b1 = (const float*)d_in[4];
  const float* W2 = (const float*)d_in[5];
  const float* b2 = (const float*)d_in[6];
  float* out = (float*)d_out;

  char* ws = (char*)d_ws;
  const size_t szA = (size_t)NROW * KP * 2;     // 20.97 MB
  unsigned short* Ab = (unsigned short*)ws;
  unsigned short* Bb = (unsigned short*)(ws + szA);   // [8192][2560] bf16 = 41.9 MB

  hipFuncSetAttribute((const void*)gemm8, hipFuncAttributeMaxDynamicSharedMemorySize, 131072);

  convAll<<<NBLK_A + NBLK_B + NBLK_P, 256, 0, stream>>>(AX, W0, Ab, Bb);
  gemm8<<<(NROW / 256) * (NPAD / 256), 512, 131072, stream>>>(Ab, Bb, b0, W1, b1, W2, b2, out);
}

// Round 10
// 204.068 us; speedup vs baseline: 1.1420x; 1.0467x over previous
//
#include <hip/hip_runtime.h>
#include <hip/hip_bf16.h>
#include <stdint.h>

#define LAG 5
#define NROW 4096
#define NREG 500
#define NTGT 500
#define O_REAL 8000     /* HH*NTGT */
#define KP 2560         /* padded K = 40*64  (real K = 2500) */
#define NPAD 8192       /* GEMM N extent = 32*256 (cols >= 8000 masked) */
#define BK 64
#define NT 40           /* K-tiles */

#define NBLK_A 10240    /* NROW*(KP/4)/256 */
#define NBLK_B 15625    /* O_REAL*NREG/256 */
#define NBLK_P 949      /* ceil((O_REAL*15 + 192*(KP/4))/256) */

typedef __bf16 bf16x8 __attribute__((ext_vector_type(8)));
typedef float f32x4 __attribute__((ext_vector_type(4)));

__device__ __forceinline__ unsigned short f2bf(float f) {
  unsigned u = __float_as_uint(f);
  return (unsigned short)((u + 0x7fffu + ((u >> 16) & 1u)) >> 16);
}

__device__ __forceinline__ void async16(void* lds_base, const void* g) {
  __builtin_amdgcn_global_load_lds(
      (const __attribute__((address_space(1))) unsigned int*)g,
      (__attribute__((address_space(3))) unsigned int*)lds_base,
      16, 0, 0);
}

// ---- merged prep: convA [0,NBLK_A) | convB [NBLK_A,NBLK_A+NBLK_B) | padB [rest) ----------------
__global__ __launch_bounds__(256) void convAll(const float* __restrict__ AX,
                                               const float* __restrict__ W0,
                                               unsigned short* __restrict__ Ab,
                                               unsigned short* __restrict__ Bb) {
  int b = blockIdx.x;
  if (b < NBLK_A) {
    int idx = b * 256 + threadIdx.x;
    int n = idx / (KP / 4);
    int c4 = idx - n * (KP / 4);
    int k = c4 * 4;
    ushort4 o;
    if (k < LAG * NREG) {
      int l = k / NREG, r = k - l * NREG;
      float4 v = *(const float4*)(AX + ((size_t)l * NROW + n) * NREG + r);
      o.x = f2bf(v.x); o.y = f2bf(v.y); o.z = f2bf(v.z); o.w = f2bf(v.w);
    } else {
      o.x = 0; o.y = 0; o.z = 0; o.w = 0;
    }
    *(ushort4*)(Ab + (size_t)idx * 4) = o;
  } else if (b < NBLK_A + NBLK_B) {
    int idx = (b - NBLK_A) * 256 + threadIdx.x;
    int o = idx / NREG, r = idx - o * NREG;
    const float* s = W0 + (size_t)idx * LAG;
    #pragma unroll
    for (int j = 0; j < LAG; ++j)
      Bb[(size_t)o * KP + (size_t)(LAG - 1 - j) * NREG + r] = f2bf(s[j]);
  } else {
    int idx = (b - NBLK_A - NBLK_B) * 256 + threadIdx.x;    // ushort4 units
    const int A4 = O_REAL * 15;                             // 60 pad elems/row
    ushort4 z; z.x = 0; z.y = 0; z.z = 0; z.w = 0;
    if (idx < A4) {
      int row = idx / 15, c4 = idx - row * 15;
      *(ushort4*)(Bb + (size_t)row * KP + 2500 + c4 * 4) = z;
    } else {
      int j = idx - A4;
      if (j < 192 * (KP / 4))
        *(ushort4*)(Bb + (size_t)O_REAL * KP + (size_t)j * 4) = z;
    }
  }
}

// ---------------- 256x256 4-phase bf16 GEMM + fused MLP tail ------------------------------------
// K-loop v9: 4 phases/iter (32 MFMA each) — halves barrier/lgkm0 count vs the verified 8-phase v4.
// Same-phase consume reads (r4-verified pattern), 2 STG (4 loads)/phase, collective vmcnt gates
// before the inter-phase barrier that precedes the gated buffer's first read.
//   ph1 (T(t) m0-3, b0): 16R bb0123+a03; STG A(t+1)->b1; lgkm(8); bar; lgkm0; 32 MFMA; bar
//   ph2 (T(t) m4-7, b0):  8R a47;        STG B(t+2)->b0.B; bar; lgkm0; 32 MFMA; GATE vm(4); bar
//   ph3 (T(t+1) m0-3,b1): 16R bb+a03;    STG A(t+2)->b0.A; lgkm(8); bar; lgkm0; 32 MFMA; bar
//   ph4 (T(t+1) m4-7,b1):  8R a47;       STG B(t+3)->b1.B; bar; lgkm0; 32 MFMA; GATE vm(4); bar
// WAR (>=1 barrier between read-retire and DMA-issue): b1.A reads retire prev ph4 lgkm0 -> STG ph1;
// b0.B retire ph1 -> STG ph2; b0.A retire ph2 -> STG ph3; b1.B retire ph3 -> STG ph4.
// RAW: ph2-END gate drains B(t+1)+A(t+1) (8 oldest of 12) before ph3/ph4 read b1; ph4-END gate
// drains B(t+2)+A(t+2) before next ph1/ph2 read b0. Last iter: ph2 gate -> vmcnt(0), rest skipped.
__global__ __launch_bounds__(512, 2) void gemm8(const unsigned short* __restrict__ A,
                                                const unsigned short* __restrict__ B,
                                                const float* __restrict__ b0,
                                                const float* __restrict__ W1g,
                                                const float* __restrict__ b1g,
                                                const float* __restrict__ W2g,
                                                const float* __restrict__ b2g,
                                                float* __restrict__ out) {
  extern __shared__ char smem[];
  char* sAc = smem;            // [2][32768]
  char* sBc = smem + 65536;    // [2][32768]

  int bid = blockIdx.x;
  int swz = (bid & 7) * 64 + (bid >> 3);       // XCD-aware, bijective (512 % 8 == 0)
  int mt = swz & 15, ntile = swz >> 4;         // 16 M-tiles x 32 N-tiles
  int row0 = mt * 256, col0 = ntile * 256;

  int tid = threadIdx.x, l = tid & 63, w = tid >> 6;
  int wr = w >> 2, wc = w & 3;

  // staging source pointers (pre-swizzled global source, linear LDS dest)
  int sr = l >> 3;                 // row within 8-row chunk
  int ss = (l & 7) ^ sr;           // swizzled 16B slot
  const unsigned short* gApre0 = A + (size_t)(row0 + (w * 2 + 0) * 8 + sr) * KP + ss * 8;
  const unsigned short* gApre1 = A + (size_t)(row0 + (w * 2 + 1) * 8 + sr) * KP + ss * 8;
  const unsigned short* gBpre0 = B + (size_t)(col0 + (w * 2 + 0) * 8 + sr) * KP + ss * 8;
  const unsigned short* gBpre1 = B + (size_t)(col0 + (w * 2 + 1) * 8 + sr) * KP + ss * 8;

#define STG_A(buf, half, t) do { \
    async16(sAc + (buf) * 32768 + (half) * 16384 + (w * 2 + 0) * 1024, gApre0 + (size_t)(half) * 128 * KP + (size_t)(t) * BK); \
    async16(sAc + (buf) * 32768 + (half) * 16384 + (w * 2 + 1) * 1024, gApre1 + (size_t)(half) * 128 * KP + (size_t)(t) * BK); \
  } while (0)
#define STG_B(buf, half, t) do { \
    async16(sBc + (buf) * 32768 + (half) * 16384 + (w * 2 + 0) * 1024, gBpre0 + (size_t)(half) * 128 * KP + (size_t)(t) * BK); \
    async16(sBc + (buf) * 32768 + (half) * 16384 + (w * 2 + 1) * 1024, gBpre1 + (size_t)(half) * 128 * KP + (size_t)(t) * BK); \
  } while (0)

  // fragment read offsets (row&7 == l&7 for all fragment rows)
  int arowb = (wr * 128 + (l & 15)) * 128;     // byte offset of A row
  int browb = (wc * 64 + (l & 15)) * 128;      // byte offset of B row
  int c0 = (((l >> 4) << 4)) ^ ((l & 7) << 4); // kk=0 swizzled col byte; kk=1 -> ^64

  auto lda = [&](int buf, int mi, int kk) -> bf16x8 {
    return *(const bf16x8*)(sAc + buf * 32768 + arowb + mi * 2048 + (c0 ^ (kk * 64)));
  };
  auto ldb = [&](int buf, int ni, int kk) -> bf16x8 {
    return *(const bf16x8*)(sBc + buf * 32768 + browb + ni * 2048 + (c0 ^ (kk * 64)));
  };

  f32x4 acc[8][4];
  #pragma unroll
  for (int i = 0; i < 8; ++i)
    #pragma unroll
    for (int j = 0; j < 4; ++j) acc[i][j] = (f32x4){0.f, 0.f, 0.f, 0.f};

// 32 MFMA: 4 mi x 4 ni x 2 kk into acc[MOFF+mi][ni]
#define MFMA_H(MOFF, AF) do { \
    _Pragma("unroll") \
    for (int mi = 0; mi < 4; ++mi) { \
      _Pragma("unroll") \
      for (int ni = 0; ni < 4; ++ni) { \
        acc[(MOFF) + mi][ni] = __builtin_amdgcn_mfma_f32_16x16x32_bf16(AF[mi][0], bb[ni][0], acc[(MOFF) + mi][ni], 0, 0, 0); \
        acc[(MOFF) + mi][ni] = __builtin_amdgcn_mfma_f32_16x16x32_bf16(AF[mi][1], bb[ni][1], acc[(MOFF) + mi][ni], 0, 0, 0); \
      } \
    } \
  } while (0)

  // prologue: T0 full {B,A} + T1.B -> 12 loads/thread; collective gate T0 (T1.B's 4 in flight)
  STG_B(0, 0, 0); STG_B(0, 1, 0); STG_A(0, 0, 0); STG_A(0, 1, 0);
  STG_B(1, 0, 1); STG_B(1, 1, 1);
  asm volatile("s_waitcnt vmcnt(4)" ::: "memory");
  __builtin_amdgcn_s_barrier();

  for (int t = 0; t < NT; t += 2) {
    const bool last = (t == NT - 2);
    bf16x8 a03[4][2], a47[4][2], bb[4][2];

    // ---- ph1: T(t) m0-3 (buf0). 16R; STG A(t+1)->b1 (b1.A reads retired prev ph4)
    #pragma unroll
    for (int ni = 0; ni < 4; ++ni) { bb[ni][0] = ldb(0, ni, 0); bb[ni][1] = ldb(0, ni, 1); }
    #pragma unroll
    for (int mi = 0; mi < 4; ++mi) { a03[mi][0] = lda(0, mi, 0); a03[mi][1] = lda(0, mi, 1); }
    STG_A(1, 0, t + 1); STG_A(1, 1, t + 1);
    asm volatile("s_waitcnt lgkmcnt(8)" ::: "memory");
    __builtin_amdgcn_s_barrier();
    asm volatile("s_waitcnt lgkmcnt(0)" ::: "memory");
    __builtin_amdgcn_s_setprio(1);
    MFMA_H(0, a03);
    __builtin_amdgcn_s_setprio(0);
    __builtin_amdgcn_s_barrier();

    // ---- ph2: T(t) m4-7. 8R a47; STG B(t+2)->b0.B (b0.B reads retired ph1); gate b1 at END
    #pragma unroll
    for (int mi = 0; mi < 4; ++mi) { a47[mi][0] = lda(0, 4 + mi, 0); a47[mi][1] = lda(0, 4 + mi, 1); }
    if (!last) { STG_B(0, 0, t + 2); STG_B(0, 1, t + 2); }
    __builtin_amdgcn_s_barrier();
    asm volatile("s_waitcnt lgkmcnt(0)" ::: "memory");
    __builtin_amdgcn_s_setprio(1);
    MFMA_H(4, a47);
    __builtin_amdgcn_s_setprio(0);
    if (last) asm volatile("s_waitcnt vmcnt(0)" ::: "memory");
    else      asm volatile("s_waitcnt vmcnt(4)" ::: "memory");
    __builtin_amdgcn_s_barrier();

    // ---- ph3: T(t+1) m0-3 (buf1). 16R; STG A(t+2)->b0.A (b0.A reads retired ph2)
    #pragma unroll
    for (int ni = 0; ni < 4; ++ni) { bb[ni][0] = ldb(1, ni, 0); bb[ni][1] = ldb(1, ni, 1); }
    #pragma unroll
    for (int mi = 0; mi < 4; ++mi) { a03[mi][0] = lda(1, mi, 0); a03[mi][1] = lda(1, mi, 1); }
    if (!last) { STG_A(0, 0, t + 2); STG_A(0, 1, t + 2); }
    asm volatile("s_waitcnt lgkmcnt(8)" ::: "memory");
    __builtin_amdgcn_s_barrier();
    asm volatile("s_waitcnt lgkmcnt(0)" ::: "memory");
    __builtin_amdgcn_s_setprio(1);
    MFMA_H(0, a03);
    __builtin_amdgcn_s_setprio(0);
    __builtin_amdgcn_s_barrier();

    // ---- ph4: T(t+1) m4-7. 8R a47; STG B(t+3)->b1.B (b1.B reads retired ph3); gate b0 at END
    #pragma unroll
    for (int mi = 0; mi < 4; ++mi) { a47[mi][0] = lda(1, 4 + mi, 0); a47[mi][1] = lda(1, 4 + mi, 1); }
    if (!last) { STG_B(1, 0, t + 3); STG_B(1, 1, t + 3); }
    __builtin_amdgcn_s_barrier();
    asm volatile("s_waitcnt lgkmcnt(0)" ::: "memory");
    __builtin_amdgcn_s_setprio(1);
    MFMA_H(4, a47);
    __builtin_amdgcn_s_setprio(0);
    if (!last) asm volatile("s_waitcnt vmcnt(4)" ::: "memory");
    __builtin_amdgcn_s_barrier();
  }

  // ================= epilogue (byte-identical to verified round-2/round-4) =================
  // Step 1: ALL waves dump acc into full 256x256 bf16 X tile (exactly 128 KiB). acc dies here.
  int lq = l >> 4, lr = l & 15;
  int t0 = col0 >> 4;                      // first of this block's 16 targets

  float bias[4];
  #pragma unroll
  for (int ni = 0; ni < 4; ++ni) {
    int gcol = col0 + wc * 64 + ni * 16 + lr;
    bias[ni] = (gcol < O_REAL) ? b0[gcol] : 0.f;
  }

  #pragma unroll
  for (int mi = 0; mi < 8; ++mi) {
    #pragma unroll
    for (int ni = 0; ni < 4; ++ni) {
      #pragma unroll
      for (int r = 0; r < 4; ++r) {
        int rowL = wr * 128 + mi * 16 + lq * 4 + r;
        int colL = wc * 64 + ni * 16 + lr;
        int sw = ((rowL ^ (rowL >> 2)) & 7) << 4;
        float v = fmaxf(acc[mi][ni][r] + bias[ni], 0.f);
        *(unsigned short*)(smem + (size_t)rowL * 512 + ((colL * 2) ^ sw)) = f2bf(v);
      }
    }
  }
  __syncthreads();

  // Step 2: wave w owns targets 2w, 2w+1; lanes = rows. W via wave-uniform (scalar) loads.
  int uw = __builtin_amdgcn_readfirstlane(w);
  float oacc[2][4];
  #pragma unroll
  for (int g = 0; g < 2; ++g) {
    int tloc = uw * 2 + g;
    int tt = t0 + tloc;
    bool tvalid = (tt < NTGT);
    const float* w1t = W1g + (size_t)tt * 256;
    float b1v[16], w2v[16];
    float b2v = 0.f;
    if (tvalid) {
      #pragma unroll
      for (int e4 = 0; e4 < 4; ++e4) {
        float4 ba = *(const float4*)(b1g + (size_t)tt * 16 + e4 * 4);
        float4 wa = *(const float4*)(W2g + (size_t)tt * 16 + e4 * 4);
        b1v[e4 * 4 + 0] = ba.x; b1v[e4 * 4 + 1] = ba.y; b1v[e4 * 4 + 2] = ba.z; b1v[e4 * 4 + 3] = ba.w;
        w2v[e4 * 4 + 0] = wa.x; w2v[e4 * 4 + 1] = wa.y; w2v[e4 * 4 + 2] = wa.z; w2v[e4 * 4 + 3] = wa.w;
      }
      b2v = b2g[tt];
    }
    #pragma unroll
    for (int rg = 0; rg < 4; ++rg) {
      int rowL = rg * 64 + l;
      int sw = ((rowL ^ (rowL >> 2)) & 7) << 4;
      const char* bp = smem + (size_t)rowL * 512;
      uint4 va = *(const uint4*)(bp + ((tloc * 32) ^ sw));
      uint4 vb = *(const uint4*)(bp + ((tloc * 32 + 16) ^ sw));
      unsigned q0 = va.x, q1 = va.y, q2 = va.z, q3 = va.w;
      unsigned q4 = vb.x, q5 = vb.y, q6 = vb.z, q7 = vb.w;
      float x[16];
      x[0]  = __uint_as_float(q0 << 16); x[1]  = __uint_as_float(q0 & 0xffff0000u);
      x[2]  = __uint_as_float(q1 << 16); x[3]  = __uint_as_float(q1 & 0xffff0000u);
      x[4]  = __uint_as_float(q2 << 16); x[5]  = __uint_as_float(q2 & 0xffff0000u);
      x[6]  = __uint_as_float(q3 << 16); x[7]  = __uint_as_float(q3 & 0xffff0000u);
      x[8]  = __uint_as_float(q4 << 16); x[9]  = __uint_as_float(q4 & 0xffff0000u);
      x[10] = __uint_as_float(q5 << 16); x[11] = __uint_as_float(q5 & 0xffff0000u);
      x[12] = __uint_as_float(q6 << 16); x[13] = __uint_as_float(q6 & 0xffff0000u);
      x[14] = __uint_as_float(q7 << 16); x[15] = __uint_as_float(q7 & 0xffff0000u);
      float o = 0.f;
      if (tvalid) {
        #pragma unroll
        for (int e = 0; e < 16; ++e) {
          float4 wq0 = *(const float4*)(w1t + e * 16 + 0);
          float4 wq1 = *(const float4*)(w1t + e * 16 + 4);
          float4 wq2 = *(const float4*)(w1t + e * 16 + 8);
          float4 wq3 = *(const float4*)(w1t + e * 16 + 12);
          float s = b1v[e];
          s = fmaf(x[0],  wq0.x, s); s = fmaf(x[1],  wq0.y, s);
          s = fmaf(x[2],  wq0.z, s); s = fmaf(x[3],  wq0.w, s);
          s = fmaf(x[4],  wq1.x, s); s = fmaf(x[5],  wq1.y, s);
          s = fmaf(x[6],  wq1.z, s); s = fmaf(x[7],  wq1.w, s);
          s = fmaf(x[8],  wq2.x, s); s = fmaf(x[9],  wq2.y, s);
          s = fmaf(x[10], wq2.z, s); s = fmaf(x[11], wq2.w, s);
          s = fmaf(x[12], wq3.x, s); s = fmaf(x[13], wq3.y, s);
          s = fmaf(x[14], wq3.z, s); s = fmaf(x[15], wq3.w, s);
          s = fmaxf(s, 0.f);
          o = fmaf(s, w2v[e], o);
        }
        o += b2v;
      }
      oacc[g][rg] = o;
    }
  }
  __syncthreads();   // everyone done reading X

  // Step 3: transpose o through LDS ([256][17] f32 = 17.4 KB over dead X), coalesced out stores
  {
    float* sOut = (float*)smem;
    #pragma unroll
    for (int g = 0; g < 2; ++g) {
      int tloc = uw * 2 + g;
      #pragma unroll
      for (int rg = 0; rg < 4; ++rg)
        sOut[(rg * 64 + l) * 17 + tloc] = oacc[g][rg];
    }
    __syncthreads();
    int c = tid & 15, rr = tid >> 4;
    bool cv = (t0 + c < NTGT);
    #pragma unroll
    for (int j = 0; j < 8; ++j) {
      int row = rr + 32 * j;
      if (cv) out[(size_t)(row0 + row) * NTGT + (t0 + c)] = sOut[row * 17 + c];
    }
  }
#undef STG_A
#undef STG_B
#undef MFMA_H
}

extern "C" void kernel_launch(void* const* d_in, const int* in_sizes, int n_in,
                              void* d_out, int out_size, void* d_ws, size_t ws_size,
                              hipStream_t stream) {
  const float* AX = (const float*)d_in[0];
  const float* W0 = (const float*)d_in[1];
  const float* b0 = (const float*)d_in[2];
  const float* W1 = (const float*)d_in[3];
  const float* b1 = (const float*)d_in[4];
  const float* W2 = (const float*)d_in[5];
  const float* b2 = (const float*)d_in[6];
  float* out = (float*)d_out;

  char* ws = (char*)d_ws;
  const size_t szA = (size_t)NROW * KP * 2;     // 20.97 MB
  unsigned short* Ab = (unsigned short*)ws;
  unsigned short* Bb = (unsigned short*)(ws + szA);   // [8192][2560] bf16 = 41.9 MB

  hipFuncSetAttribute((const void*)gemm8, hipFuncAttributeMaxDynamicSharedMemorySize, 131072);

  convAll<<<NBLK_A + NBLK_B + NBLK_P, 256, 0, stream>>>(AX, W0, Ab, Bb);
  gemm8<<<(NROW / 256) * (NPAD / 256), 512, 131072, stream>>>(Ab, Bb, b0, W1, b1, W2, b2, out);
}

// Round 11
// 203.720 us; speedup vs baseline: 1.1439x; 1.0017x over previous
//
#include <hip/hip_runtime.h>
#include <hip/hip_bf16.h>
#include <stdint.h>

#define LAG 5
#define NROW 4096
#define NREG 500
#define NTGT 500
#define O_REAL 8000     /* HH*NTGT */
#define KP 2560         /* padded K = 40*64  (real K = 2500) */
#define NPAD 8192       /* GEMM N extent = 32*256 (cols >= 8000 masked) */
#define BK 64
#define NT 40           /* K-tiles */

#define NBLK_A 10240    /* NROW*(KP/4)/256 */
#define NBLK_B 15625    /* O_REAL*NREG/256 */
#define NBLK_P 949      /* ceil((O_REAL*15 + 192*(KP/4))/256) */

typedef __bf16 bf16x8 __attribute__((ext_vector_type(8)));
typedef float f32x4 __attribute__((ext_vector_type(4)));

__device__ __forceinline__ unsigned short f2bf(float f) {
  unsigned u = __float_as_uint(f);
  return (unsigned short)((u + 0x7fffu + ((u >> 16) & 1u)) >> 16);
}

__device__ __forceinline__ void async16(void* lds_base, const void* g) {
  __builtin_amdgcn_global_load_lds(
      (const __attribute__((address_space(1))) unsigned int*)g,
      (__attribute__((address_space(3))) unsigned int*)lds_base,
      16, 0, 0);
}

// ---- merged prep: convA [0,NBLK_A) | convB [NBLK_A,NBLK_A+NBLK_B) | padB [rest) ----------------
__global__ __launch_bounds__(256) void convAll(const float* __restrict__ AX,
                                               const float* __restrict__ W0,
                                               unsigned short* __restrict__ Ab,
                                               unsigned short* __restrict__ Bb) {
  int b = blockIdx.x;
  if (b < NBLK_A) {
    int idx = b * 256 + threadIdx.x;
    int n = idx / (KP / 4);
    int c4 = idx - n * (KP / 4);
    int k = c4 * 4;
    ushort4 o;
    if (k < LAG * NREG) {
      int l = k / NREG, r = k - l * NREG;
      float4 v = *(const float4*)(AX + ((size_t)l * NROW + n) * NREG + r);
      o.x = f2bf(v.x); o.y = f2bf(v.y); o.z = f2bf(v.z); o.w = f2bf(v.w);
    } else {
      o.x = 0; o.y = 0; o.z = 0; o.w = 0;
    }
    *(ushort4*)(Ab + (size_t)idx * 4) = o;
  } else if (b < NBLK_A + NBLK_B) {
    int idx = (b - NBLK_A) * 256 + threadIdx.x;
    int o = idx / NREG, r = idx - o * NREG;
    const float* s = W0 + (size_t)idx * LAG;
    #pragma unroll
    for (int j = 0; j < LAG; ++j)
      Bb[(size_t)o * KP + (size_t)(LAG - 1 - j) * NREG + r] = f2bf(s[j]);
  } else {
    int idx = (b - NBLK_A - NBLK_B) * 256 + threadIdx.x;    // ushort4 units
    const int A4 = O_REAL * 15;                             // 60 pad elems/row
    ushort4 z; z.x = 0; z.y = 0; z.z = 0; z.w = 0;
    if (idx < A4) {
      int row = idx / 15, c4 = idx - row * 15;
      *(ushort4*)(Bb + (size_t)row * KP + 2500 + c4 * 4) = z;
    } else {
      int j = idx - A4;
      if (j < 192 * (KP / 4))
        *(ushort4*)(Bb + (size_t)O_REAL * KP + (size_t)j * 4) = z;
    }
  }
}

// ---------------- 256x256 8-phase bf16 GEMM + fused MLP tail ------------------------------------
// K-loop v10: verified v4 reads/MFMA/barriers (12/4/8/0 same-phase consume) with DEEPER staging:
// slots ph1:A(t+1)h1 | ph3:B(t+2)h0 | ph4:B(t+2)h1+A(t+2)h0 | ph5:A(t+2)h1 | ph7:B(t+3)h0 |
// ph8:B(t+3)h1+A(t+3)h0 (A-h0 hoisted one iter early). Min prefetch slack 2 -> 3 phases; both
// gates become vmcnt(6) (3 half-tiles in flight) — the m201 constant.
// WAR: A(t+2)h0@ph4 after buf0.A retires ph3-lgkm0 (1 barrier) ; A(t+3)h0@ph8 after buf1.A
// retires ph7-lgkm0 ; B slots unchanged from v4. RAW: ph4/ph8 gates drain exactly the next tile
// (queue = 14, oldest 8 = tile; proof in session notes). Last iter: STGs guarded off, gates vm(0).
__global__ __launch_bounds__(512, 2) void gemm8(const unsigned short* __restrict__ A,
                                                const unsigned short* __restrict__ B,
                                                const float* __restrict__ b0,
                                                const float* __restrict__ W1g,
                                                const float* __restrict__ b1g,
                                                const float* __restrict__ W2g,
                                                const float* __restrict__ b2g,
                                                float* __restrict__ out) {
  extern __shared__ char smem[];
  char* sAc = smem;            // [2][32768]
  char* sBc = smem + 65536;    // [2][32768]

  int bid = blockIdx.x;
  int swz = (bid & 7) * 64 + (bid >> 3);       // XCD-aware, bijective (512 % 8 == 0)
  int mt = swz & 15, ntile = swz >> 4;         // 16 M-tiles x 32 N-tiles
  int row0 = mt * 256, col0 = ntile * 256;

  int tid = threadIdx.x, l = tid & 63, w = tid >> 6;
  int wr = w >> 2, wc = w & 3;

  // staging source pointers (pre-swizzled global source, linear LDS dest)
  int sr = l >> 3;                 // row within 8-row chunk
  int ss = (l & 7) ^ sr;           // swizzled 16B slot
  const unsigned short* gApre0 = A + (size_t)(row0 + (w * 2 + 0) * 8 + sr) * KP + ss * 8;
  const unsigned short* gApre1 = A + (size_t)(row0 + (w * 2 + 1) * 8 + sr) * KP + ss * 8;
  const unsigned short* gBpre0 = B + (size_t)(col0 + (w * 2 + 0) * 8 + sr) * KP + ss * 8;
  const unsigned short* gBpre1 = B + (size_t)(col0 + (w * 2 + 1) * 8 + sr) * KP + ss * 8;

#define STG_A(buf, half, t) do { \
    async16(sAc + (buf) * 32768 + (half) * 16384 + (w * 2 + 0) * 1024, gApre0 + (size_t)(half) * 128 * KP + (size_t)(t) * BK); \
    async16(sAc + (buf) * 32768 + (half) * 16384 + (w * 2 + 1) * 1024, gApre1 + (size_t)(half) * 128 * KP + (size_t)(t) * BK); \
  } while (0)
#define STG_B(buf, half, t) do { \
    async16(sBc + (buf) * 32768 + (half) * 16384 + (w * 2 + 0) * 1024, gBpre0 + (size_t)(half) * 128 * KP + (size_t)(t) * BK); \
    async16(sBc + (buf) * 32768 + (half) * 16384 + (w * 2 + 1) * 1024, gBpre1 + (size_t)(half) * 128 * KP + (size_t)(t) * BK); \
  } while (0)

  // fragment read offsets (row&7 == l&7 for all fragment rows)
  int arowb = (wr * 128 + (l & 15)) * 128;     // byte offset of A row
  int browb = (wc * 64 + (l & 15)) * 128;      // byte offset of B row
  int c0 = (((l >> 4) << 4)) ^ ((l & 7) << 4); // kk=0 swizzled col byte; kk=1 -> ^64

  auto lda = [&](int buf, int mi, int kk) -> bf16x8 {
    return *(const bf16x8*)(sAc + buf * 32768 + arowb + mi * 2048 + (c0 ^ (kk * 64)));
  };
  auto ldb = [&](int buf, int ni, int kk) -> bf16x8 {
    return *(const bf16x8*)(sBc + buf * 32768 + browb + ni * 2048 + (c0 ^ (kk * 64)));
  };

  f32x4 acc[8][4];
  #pragma unroll
  for (int i = 0; i < 8; ++i)
    #pragma unroll
    for (int j = 0; j < 4; ++j) acc[i][j] = (f32x4){0.f, 0.f, 0.f, 0.f};

#define PH_SYNC() do { __builtin_amdgcn_s_barrier(); \
    asm volatile("s_waitcnt lgkmcnt(0)" ::: "memory"); \
    __builtin_amdgcn_s_setprio(1); } while (0)
#define PH_END() do { __builtin_amdgcn_s_setprio(0); __builtin_amdgcn_s_barrier(); } while (0)

#define MFMA_Q(MOFF, AF, NIOFF) do { \
    _Pragma("unroll") \
    for (int mi = 0; mi < 4; ++mi) { \
      _Pragma("unroll") \
      for (int ni = 0; ni < 2; ++ni) { \
        acc[(MOFF) + mi][(NIOFF) + ni] = __builtin_amdgcn_mfma_f32_16x16x32_bf16(AF[mi][0], bb[(NIOFF) + ni][0], acc[(MOFF) + mi][(NIOFF) + ni], 0, 0, 0); \
        acc[(MOFF) + mi][(NIOFF) + ni] = __builtin_amdgcn_mfma_f32_16x16x32_bf16(AF[mi][1], bb[(NIOFF) + ni][1], acc[(MOFF) + mi][(NIOFF) + ni], 0, 0, 0); \
      } \
    } \
  } while (0)

  // prologue: T0 full {B,A} + B(1)h0,h1 + A(1)h0 -> 14 loads/thread; gate T0 (6 in flight)
  STG_B(0, 0, 0); STG_B(0, 1, 0); STG_A(0, 0, 0); STG_A(0, 1, 0);
  STG_B(1, 0, 1); STG_B(1, 1, 1); STG_A(1, 0, 1);
  asm volatile("s_waitcnt vmcnt(6)" ::: "memory");
  __builtin_amdgcn_s_barrier();

  for (int t = 0; t < NT; t += 2) {
    const bool last = (t == NT - 2);
    bf16x8 a03[4][2], a47[4][2], bb[4][2];

    // ---- ph1: read bb01+a03 (buf0, 12R); stage A(t+1)h1 (h0 staged prev ph8 / prologue)
    #pragma unroll
    for (int ni = 0; ni < 2; ++ni) { bb[ni][0] = ldb(0, ni, 0); bb[ni][1] = ldb(0, ni, 1); }
    #pragma unroll
    for (int mi = 0; mi < 4; ++mi) { a03[mi][0] = lda(0, mi, 0); a03[mi][1] = lda(0, mi, 1); }
    STG_A(1, 1, t + 1);
    asm volatile("s_waitcnt lgkmcnt(8)" ::: "memory");
    PH_SYNC(); MFMA_Q(0, a03, 0); PH_END();

    // ---- ph2: read bb23 (4R); no staging
    #pragma unroll
    for (int ni = 2; ni < 4; ++ni) { bb[ni][0] = ldb(0, ni, 0); bb[ni][1] = ldb(0, ni, 1); }
    PH_SYNC(); MFMA_Q(0, a03, 2); PH_END();

    // ---- ph3: read a47 (8R); stage B(t+2)h0 (buf0.B reads retired ph2-END)
    #pragma unroll
    for (int mi = 0; mi < 4; ++mi) { a47[mi][0] = lda(0, 4 + mi, 0); a47[mi][1] = lda(0, 4 + mi, 1); }
    if (!last) STG_B(0, 0, t + 2);
    PH_SYNC(); MFMA_Q(4, a47, 0); PH_END();

    // ---- ph4: stage B(t+2)h1 + A(t+2)h0 (buf0.A reads retired ph3-END); GATE tile t+1 vm(6)
    if (!last) { STG_B(0, 1, t + 2); STG_A(0, 0, t + 2); }
    if (last) asm volatile("s_waitcnt vmcnt(0)" ::: "memory");
    else      asm volatile("s_waitcnt vmcnt(6)" ::: "memory");
    __builtin_amdgcn_s_barrier();
    asm volatile("s_waitcnt lgkmcnt(0)" ::: "memory");
    __builtin_amdgcn_s_setprio(1);
    MFMA_Q(4, a47, 2);
    PH_END();

    // ---- ph5: read bb01+a03 (buf1, 12R); stage A(t+2)h1
    #pragma unroll
    for (int ni = 0; ni < 2; ++ni) { bb[ni][0] = ldb(1, ni, 0); bb[ni][1] = ldb(1, ni, 1); }
    #pragma unroll
    for (int mi = 0; mi < 4; ++mi) { a03[mi][0] = lda(1, mi, 0); a03[mi][1] = lda(1, mi, 1); }
    if (!last) STG_A(0, 1, t + 2);
    asm volatile("s_waitcnt lgkmcnt(8)" ::: "memory");
    PH_SYNC(); MFMA_Q(0, a03, 0); PH_END();

    // ---- ph6: read bb23 (buf1, 4R); no staging
    #pragma unroll
    for (int ni = 2; ni < 4; ++ni) { bb[ni][0] = ldb(1, ni, 0); bb[ni][1] = ldb(1, ni, 1); }
    PH_SYNC(); MFMA_Q(0, a03, 2); PH_END();

    // ---- ph7: read a47 (buf1, 8R); stage B(t+3)h0 (buf1.B reads retired ph6-END)
    #pragma unroll
    for (int mi = 0; mi < 4; ++mi) { a47[mi][0] = lda(1, 4 + mi, 0); a47[mi][1] = lda(1, 4 + mi, 1); }
    if (!last) STG_B(1, 0, t + 3);
    PH_SYNC(); MFMA_Q(4, a47, 0); PH_END();

    // ---- ph8: stage B(t+3)h1 + A(t+3)h0 (buf1.A reads retired ph7-END); GATE tile t+2 vm(6)
    if (!last) { STG_B(1, 1, t + 3); STG_A(1, 0, t + 3); }
    if (last) asm volatile("s_waitcnt vmcnt(0)" ::: "memory");
    else      asm volatile("s_waitcnt vmcnt(6)" ::: "memory");
    __builtin_amdgcn_s_barrier();
    asm volatile("s_waitcnt lgkmcnt(0)" ::: "memory");
    __builtin_amdgcn_s_setprio(1);
    MFMA_Q(4, a47, 2);
    __builtin_amdgcn_s_setprio(0);
    __builtin_amdgcn_s_barrier();
  }

  // ================= epilogue (byte-identical to verified round-2/round-4) =================
  // Step 1: ALL waves dump acc into full 256x256 bf16 X tile (exactly 128 KiB). acc dies here.
  int lq = l >> 4, lr = l & 15;
  int t0 = col0 >> 4;                      // first of this block's 16 targets

  float bias[4];
  #pragma unroll
  for (int ni = 0; ni < 4; ++ni) {
    int gcol = col0 + wc * 64 + ni * 16 + lr;
    bias[ni] = (gcol < O_REAL) ? b0[gcol] : 0.f;
  }

  #pragma unroll
  for (int mi = 0; mi < 8; ++mi) {
    #pragma unroll
    for (int ni = 0; ni < 4; ++ni) {
      #pragma unroll
      for (int r = 0; r < 4; ++r) {
        int rowL = wr * 128 + mi * 16 + lq * 4 + r;
        int colL = wc * 64 + ni * 16 + lr;
        int sw = ((rowL ^ (rowL >> 2)) & 7) << 4;
        float v = fmaxf(acc[mi][ni][r] + bias[ni], 0.f);
        *(unsigned short*)(smem + (size_t)rowL * 512 + ((colL * 2) ^ sw)) = f2bf(v);
      }
    }
  }
  __syncthreads();

  // Step 2: wave w owns targets 2w, 2w+1; lanes = rows. W via wave-uniform (scalar) loads.
  int uw = __builtin_amdgcn_readfirstlane(w);
  float oacc[2][4];
  #pragma unroll
  for (int g = 0; g < 2; ++g) {
    int tloc = uw * 2 + g;
    int tt = t0 + tloc;
    bool tvalid = (tt < NTGT);
    const float* w1t = W1g + (size_t)tt * 256;
    float b1v[16], w2v[16];
    float b2v = 0.f;
    if (tvalid) {
      #pragma unroll
      for (int e4 = 0; e4 < 4; ++e4) {
        float4 ba = *(const float4*)(b1g + (size_t)tt * 16 + e4 * 4);
        float4 wa = *(const float4*)(W2g + (size_t)tt * 16 + e4 * 4);
        b1v[e4 * 4 + 0] = ba.x; b1v[e4 * 4 + 1] = ba.y; b1v[e4 * 4 + 2] = ba.z; b1v[e4 * 4 + 3] = ba.w;
        w2v[e4 * 4 + 0] = wa.x; w2v[e4 * 4 + 1] = wa.y; w2v[e4 * 4 + 2] = wa.z; w2v[e4 * 4 + 3] = wa.w;
      }
      b2v = b2g[tt];
    }
    #pragma unroll
    for (int rg = 0; rg < 4; ++rg) {
      int rowL = rg * 64 + l;
      int sw = ((rowL ^ (rowL >> 2)) & 7) << 4;
      const char* bp = smem + (size_t)rowL * 512;
      uint4 va = *(const uint4*)(bp + ((tloc * 32) ^ sw));
      uint4 vb = *(const uint4*)(bp + ((tloc * 32 + 16) ^ sw));
      unsigned q0 = va.x, q1 = va.y, q2 = va.z, q3 = va.w;
      unsigned q4 = vb.x, q5 = vb.y, q6 = vb.z, q7 = vb.w;
      float x[16];
      x[0]  = __uint_as_float(q0 << 16); x[1]  = __uint_as_float(q0 & 0xffff0000u);
      x[2]  = __uint_as_float(q1 << 16); x[3]  = __uint_as_float(q1 & 0xffff0000u);
      x[4]  = __uint_as_float(q2 << 16); x[5]  = __uint_as_float(q2 & 0xffff0000u);
      x[6]  = __uint_as_float(q3 << 16); x[7]  = __uint_as_float(q3 & 0xffff0000u);
      x[8]  = __uint_as_float(q4 << 16); x[9]  = __uint_as_float(q4 & 0xffff0000u);
      x[10] = __uint_as_float(q5 << 16); x[11] = __uint_as_float(q5 & 0xffff0000u);
      x[12] = __uint_as_float(q6 << 16); x[13] = __uint_as_float(q6 & 0xffff0000u);
      x[14] = __uint_as_float(q7 << 16); x[15] = __uint_as_float(q7 & 0xffff0000u);
      float o = 0.f;
      if (tvalid) {
        #pragma unroll
        for (int e = 0; e < 16; ++e) {
          float4 wq0 = *(const float4*)(w1t + e * 16 + 0);
          float4 wq1 = *(const float4*)(w1t + e * 16 + 4);
          float4 wq2 = *(const float4*)(w1t + e * 16 + 8);
          float4 wq3 = *(const float4*)(w1t + e * 16 + 12);
          float s = b1v[e];
          s = fmaf(x[0],  wq0.x, s); s = fmaf(x[1],  wq0.y, s);
          s = fmaf(x[2],  wq0.z, s); s = fmaf(x[3],  wq0.w, s);
          s = fmaf(x[4],  wq1.x, s); s = fmaf(x[5],  wq1.y, s);
          s = fmaf(x[6],  wq1.z, s); s = fmaf(x[7],  wq1.w, s);
          s = fmaf(x[8],  wq2.x, s); s = fmaf(x[9],  wq2.y, s);
          s = fmaf(x[10], wq2.z, s); s = fmaf(x[11], wq2.w, s);
          s = fmaf(x[12], wq3.x, s); s = fmaf(x[13], wq3.y, s);
          s = fmaf(x[14], wq3.z, s); s = fmaf(x[15], wq3.w, s);
          s = fmaxf(s, 0.f);
          o = fmaf(s, w2v[e], o);
        }
        o += b2v;
      }
      oacc[g][rg] = o;
    }
  }
  __syncthreads();   // everyone done reading X

  // Step 3: transpose o through LDS ([256][17] f32 = 17.4 KB over dead X), coalesced out stores
  {
    float* sOut = (float*)smem;
    #pragma unroll
    for (int g = 0; g < 2; ++g) {
      int tloc = uw * 2 + g;
      #pragma unroll
      for (int rg = 0; rg < 4; ++rg)
        sOut[(rg * 64 + l) * 17 + tloc] = oacc[g][rg];
    }
    __syncthreads();
    int c = tid & 15, rr = tid >> 4;
    bool cv = (t0 + c < NTGT);
    #pragma unroll
    for (int j = 0; j < 8; ++j) {
      int row = rr + 32 * j;
      if (cv) out[(size_t)(row0 + row) * NTGT + (t0 + c)] = sOut[row * 17 + c];
    }
  }
#undef STG_A
#undef STG_B
#undef PH_SYNC
#undef PH_END
#undef MFMA_Q
}

extern "C" void kernel_launch(void* const* d_in, const int* in_sizes, int n_in,
                              void* d_out, int out_size, void* d_ws, size_t ws_size,
                              hipStream_t stream) {
  const float* AX = (const float*)d_in[0];
  const float* W0 = (const float*)d_in[1];
  const float* b0 = (const float*)d_in[2];
  const float* W1 = (const float*)d_in[3];
  const float* b1 = (const float*)d_in[4];
  const float* W2 = (const float*)d_in[5];
  const float* b2 = (const float*)d_in[6];
  float* out = (float*)d_out;

  char* ws = (char*)d_ws;
  const size_t szA = (size_t)NROW * KP * 2;     // 20.97 MB
  unsigned short* Ab = (unsigned short*)ws;
  unsigned short* Bb = (unsigned short*)(ws + szA);   // [8192][2560] bf16 = 41.9 MB

  hipFuncSetAttribute((const void*)gemm8, hipFuncAttributeMaxDynamicSharedMemorySize, 131072);

  convAll<<<NBLK_A + NBLK_B + NBLK_P, 256, 0, stream>>>(AX, W0, Ab, Bb);
  gemm8<<<(NROW / 256) * (NPAD / 256), 512, 131072, stream>>>(Ab, Bb, b0, W1, b1, W2, b2, out);
}

// Round 12
// 201.283 us; speedup vs baseline: 1.1578x; 1.0121x over previous
//
#include <hip/hip_runtime.h>
#include <hip/hip_bf16.h>
#include <stdint.h>

#define LAG 5
#define NROW 4096
#define NREG 500
#define NTGT 500
#define O_REAL 8000     /* HH*NTGT */
#define KP 2560         /* padded K = 40*64  (real K = 2500) */
#define NPAD 8192       /* GEMM N extent = 32*256 (cols >= 8000 masked) */
#define BK 64
#define NT 40           /* K-tiles */

#define NBLK_A 10240    /* NROW*(KP/4)/256 */
#define NBLK_B 15625    /* O_REAL*NREG/256 */
#define NBLK_P 949      /* ceil((O_REAL*15 + 192*(KP/4))/256) */

typedef __bf16 bf16x8 __attribute__((ext_vector_type(8)));
typedef float f32x4 __attribute__((ext_vector_type(4)));

__device__ __forceinline__ unsigned short f2bf(float f) {
  unsigned u = __float_as_uint(f);
  return (unsigned short)((u + 0x7fffu + ((u >> 16) & 1u)) >> 16);
}

__device__ __forceinline__ void async16(void* lds_base, const void* g) {
  __builtin_amdgcn_global_load_lds(
      (const __attribute__((address_space(1))) unsigned int*)g,
      (__attribute__((address_space(3))) unsigned int*)lds_base,
      16, 0, 0);
}

// ---- merged prep: convA [0,NBLK_A) | convB [NBLK_A,NBLK_A+NBLK_B) | padB [rest) ----------------
__global__ __launch_bounds__(256) void convAll(const float* __restrict__ AX,
                                               const float* __restrict__ W0,
                                               unsigned short* __restrict__ Ab,
                                               unsigned short* __restrict__ Bb) {
  int b = blockIdx.x;
  if (b < NBLK_A) {
    int idx = b * 256 + threadIdx.x;
    int n = idx / (KP / 4);
    int c4 = idx - n * (KP / 4);
    int k = c4 * 4;
    ushort4 o;
    if (k < LAG * NREG) {
      int l = k / NREG, r = k - l * NREG;
      float4 v = *(const float4*)(AX + ((size_t)l * NROW + n) * NREG + r);
      o.x = f2bf(v.x); o.y = f2bf(v.y); o.z = f2bf(v.z); o.w = f2bf(v.w);
    } else {
      o.x = 0; o.y = 0; o.z = 0; o.w = 0;
    }
    *(ushort4*)(Ab + (size_t)idx * 4) = o;
  } else if (b < NBLK_A + NBLK_B) {
    int idx = (b - NBLK_A) * 256 + threadIdx.x;
    int o = idx / NREG, r = idx - o * NREG;
    const float* s = W0 + (size_t)idx * LAG;
    #pragma unroll
    for (int j = 0; j < LAG; ++j)
      Bb[(size_t)o * KP + (size_t)(LAG - 1 - j) * NREG + r] = f2bf(s[j]);
  } else {
    int idx = (b - NBLK_A - NBLK_B) * 256 + threadIdx.x;    // ushort4 units
    const int A4 = O_REAL * 15;                             // 60 pad elems/row
    ushort4 z; z.x = 0; z.y = 0; z.z = 0; z.w = 0;
    if (idx < A4) {
      int row = idx / 15, c4 = idx - row * 15;
      *(ushort4*)(Bb + (size_t)row * KP + 2500 + c4 * 4) = z;
    } else {
      int j = idx - A4;
      if (j < 192 * (KP / 4))
        *(ushort4*)(Bb + (size_t)O_REAL * KP + (size_t)j * 4) = z;
    }
  }
}

// ---------------- 256x256 8-phase bf16 GEMM + fused MLP tail ------------------------------------
// FINAL (best measured, round-7 config): v4 skeleton with balanced reads 8/4/8/4 — bb01 reads in
// the gate phases ph4/ph8, issued AFTER the vmcnt gate + barrier + lgkm0 and BEFORE the MFMA issue.
// bb[] is loop-carried: written ph4/ph8/prologue, consumed ph1-ph3 / ph5-ph7.
// Hazard map: buf0.B reads retire ph2-END -> B(t+2) ph3/ph4; buf0.A retire ph3-END ->
// A(t+2) ph5/ph6; buf1.B retire ph6-END -> B(t+3) ph7/ph8; buf1.A retire ph7-END -> A(t+1) ph1/ph2.
// Session floor note: seven single-variable K-loop experiments (read placement x2, MFMA shape,
// 128-tile residency, counted-lgkm read-ahead, 4-phase sync-halving, vmcnt(6) depth) were all
// null or negative vs this configuration — the serial LDS-read bill + barrier lockstep is the
// structural limit at HIP source level for this shape.
__global__ __launch_bounds__(512, 2) void gemm8(const unsigned short* __restrict__ A,
                                                const unsigned short* __restrict__ B,
                                                const float* __restrict__ b0,
                                                const float* __restrict__ W1g,
                                                const float* __restrict__ b1g,
                                                const float* __restrict__ W2g,
                                                const float* __restrict__ b2g,
                                                float* __restrict__ out) {
  extern __shared__ char smem[];
  char* sAc = smem;            // [2][32768]
  char* sBc = smem + 65536;    // [2][32768]

  int bid = blockIdx.x;
  int swz = (bid & 7) * 64 + (bid >> 3);       // XCD-aware, bijective (512 % 8 == 0)
  int mt = swz & 15, ntile = swz >> 4;         // 16 M-tiles x 32 N-tiles
  int row0 = mt * 256, col0 = ntile * 256;

  int tid = threadIdx.x, l = tid & 63, w = tid >> 6;
  int wr = w >> 2, wc = w & 3;

  // staging source pointers (pre-swizzled global source, linear LDS dest)
  int sr = l >> 3;                 // row within 8-row chunk
  int ss = (l & 7) ^ sr;           // swizzled 16B slot
  const unsigned short* gApre0 = A + (size_t)(row0 + (w * 2 + 0) * 8 + sr) * KP + ss * 8;
  const unsigned short* gApre1 = A + (size_t)(row0 + (w * 2 + 1) * 8 + sr) * KP + ss * 8;
  const unsigned short* gBpre0 = B + (size_t)(col0 + (w * 2 + 0) * 8 + sr) * KP + ss * 8;
  const unsigned short* gBpre1 = B + (size_t)(col0 + (w * 2 + 1) * 8 + sr) * KP + ss * 8;

#define STG_A(buf, half, t) do { \
    async16(sAc + (buf) * 32768 + (half) * 16384 + (w * 2 + 0) * 1024, gApre0 + (size_t)(half) * 128 * KP + (size_t)(t) * BK); \
    async16(sAc + (buf) * 32768 + (half) * 16384 + (w * 2 + 1) * 1024, gApre1 + (size_t)(half) * 128 * KP + (size_t)(t) * BK); \
  } while (0)
#define STG_B(buf, half, t) do { \
    async16(sBc + (buf) * 32768 + (half) * 16384 + (w * 2 + 0) * 1024, gBpre0 + (size_t)(half) * 128 * KP + (size_t)(t) * BK); \
    async16(sBc + (buf) * 32768 + (half) * 16384 + (w * 2 + 1) * 1024, gBpre1 + (size_t)(half) * 128 * KP + (size_t)(t) * BK); \
  } while (0)

  // fragment read offsets (row&7 == l&7 for all fragment rows)
  int arowb = (wr * 128 + (l & 15)) * 128;     // byte offset of A row
  int browb = (wc * 64 + (l & 15)) * 128;      // byte offset of B row
  int c0 = (((l >> 4) << 4)) ^ ((l & 7) << 4); // kk=0 swizzled col byte; kk=1 -> ^64

  auto lda = [&](int buf, int mi, int kk) -> bf16x8 {
    return *(const bf16x8*)(sAc + buf * 32768 + arowb + mi * 2048 + (c0 ^ (kk * 64)));
  };
  auto ldb = [&](int buf, int ni, int kk) -> bf16x8 {
    return *(const bf16x8*)(sBc + buf * 32768 + browb + ni * 2048 + (c0 ^ (kk * 64)));
  };

  f32x4 acc[8][4];
  #pragma unroll
  for (int i = 0; i < 8; ++i)
    #pragma unroll
    for (int j = 0; j < 4; ++j) acc[i][j] = (f32x4){0.f, 0.f, 0.f, 0.f};

#define PH_SYNC() do { __builtin_amdgcn_s_barrier(); \
    asm volatile("s_waitcnt lgkmcnt(0)" ::: "memory"); \
    __builtin_amdgcn_s_setprio(1); } while (0)
#define PH_END() do { __builtin_amdgcn_s_setprio(0); __builtin_amdgcn_s_barrier(); } while (0)

#define MFMA_Q(MOFF, AF, NIOFF) do { \
    _Pragma("unroll") \
    for (int mi = 0; mi < 4; ++mi) { \
      _Pragma("unroll") \
      for (int ni = 0; ni < 2; ++ni) { \
        acc[(MOFF) + mi][(NIOFF) + ni] = __builtin_amdgcn_mfma_f32_16x16x32_bf16(AF[mi][0], bb[(NIOFF) + ni][0], acc[(MOFF) + mi][(NIOFF) + ni], 0, 0, 0); \
        acc[(MOFF) + mi][(NIOFF) + ni] = __builtin_amdgcn_mfma_f32_16x16x32_bf16(AF[mi][1], bb[(NIOFF) + ni][1], acc[(MOFF) + mi][(NIOFF) + ni], 0, 0, 0); \
      } \
    } \
  } while (0)

  // prologue: T0 full {B,A} + T1.B -> 12 loads/thread; gate T0 (T1.B's 4 in flight)
  STG_B(0, 0, 0); STG_B(0, 1, 0); STG_A(0, 0, 0); STG_A(0, 1, 0);
  STG_B(1, 0, 1); STG_B(1, 1, 1);
  asm volatile("s_waitcnt vmcnt(4)" ::: "memory");
  __builtin_amdgcn_s_barrier();

  bf16x8 bb[4][2];     // loop-carried: bb01 written in gate phases / prologue
  #pragma unroll
  for (int ni = 0; ni < 2; ++ni) { bb[ni][0] = ldb(0, ni, 0); bb[ni][1] = ldb(0, ni, 1); }

  for (int t = 0; t < NT; t += 2) {
    const bool last = (t == NT - 2);
    bf16x8 a03[4][2], a47[4][2];

    // ---- ph1: read a03 (buf0, 8R); stage A(t+1)->buf1.h0 (buf1.A reads retired prev ph7-END)
    #pragma unroll
    for (int mi = 0; mi < 4; ++mi) { a03[mi][0] = lda(0, mi, 0); a03[mi][1] = lda(0, mi, 1); }
    STG_A(1, 0, t + 1);
    PH_SYNC(); MFMA_Q(0, a03, 0); PH_END();

    // ---- ph2: read bb23 (4R); stage A(t+1)->buf1.h1
    #pragma unroll
    for (int ni = 2; ni < 4; ++ni) { bb[ni][0] = ldb(0, ni, 0); bb[ni][1] = ldb(0, ni, 1); }
    STG_A(1, 1, t + 1);
    PH_SYNC(); MFMA_Q(0, a03, 2); PH_END();

    // ---- ph3: read a47 (8R); stage B(t+2)->buf0.h0 (buf0.B reads retired ph2-END)
    #pragma unroll
    for (int mi = 0; mi < 4; ++mi) { a47[mi][0] = lda(0, 4 + mi, 0); a47[mi][1] = lda(0, 4 + mi, 1); }
    if (!last) STG_B(0, 0, t + 2);
    PH_SYNC(); MFMA_Q(4, a47, 0); PH_END();

    // ---- ph4: stage B(t+2)->buf0.h1; GATE tile t+1; post-gate read bb01(buf1) for ph5 (4R)
    if (!last) STG_B(0, 1, t + 2);
    if (last) asm volatile("s_waitcnt vmcnt(0)" ::: "memory");
    else      asm volatile("s_waitcnt vmcnt(4)" ::: "memory");
    __builtin_amdgcn_s_barrier();
    asm volatile("s_waitcnt lgkmcnt(0)" ::: "memory");
    #pragma unroll
    for (int ni = 0; ni < 2; ++ni) { bb[ni][0] = ldb(1, ni, 0); bb[ni][1] = ldb(1, ni, 1); }
    __builtin_amdgcn_s_setprio(1);
    MFMA_Q(4, a47, 2);
    PH_END();

    // ---- ph5: read a03 (buf1, 8R); stage A(t+2)->buf0.h0 (buf0.A reads retired ph3-END)
    #pragma unroll
    for (int mi = 0; mi < 4; ++mi) { a03[mi][0] = lda(1, mi, 0); a03[mi][1] = lda(1, mi, 1); }
    if (!last) STG_A(0, 0, t + 2);
    PH_SYNC(); MFMA_Q(0, a03, 0); PH_END();

    // ---- ph6: read bb23 (buf1, 4R); stage A(t+2)->buf0.h1
    #pragma unroll
    for (int ni = 2; ni < 4; ++ni) { bb[ni][0] = ldb(1, ni, 0); bb[ni][1] = ldb(1, ni, 1); }
    if (!last) STG_A(0, 1, t + 2);
    PH_SYNC(); MFMA_Q(0, a03, 2); PH_END();

    // ---- ph7: read a47 (buf1, 8R); stage B(t+3)->buf1.h0 (buf1.B reads retired ph6-END)
    #pragma unroll
    for (int mi = 0; mi < 4; ++mi) { a47[mi][0] = lda(1, 4 + mi, 0); a47[mi][1] = lda(1, 4 + mi, 1); }
    if (!last) STG_B(1, 0, t + 3);
    PH_SYNC(); MFMA_Q(4, a47, 0); PH_END();

    // ---- ph8: stage B(t+3)->buf1.h1; GATE tile t+2; post-gate read bb01(buf0 = T(t+2)) (4R)
    if (!last) STG_B(1, 1, t + 3);
    if (last) asm volatile("s_waitcnt vmcnt(0)" ::: "memory");
    else      asm volatile("s_waitcnt vmcnt(4)" ::: "memory");
    __builtin_amdgcn_s_barrier();
    asm volatile("s_waitcnt lgkmcnt(0)" ::: "memory");
    if (!last) {
      #pragma unroll
      for (int ni = 0; ni < 2; ++ni) { bb[ni][0] = ldb(0, ni, 0); bb[ni][1] = ldb(0, ni, 1); }
    }
    __builtin_amdgcn_s_setprio(1);
    MFMA_Q(4, a47, 2);
    __builtin_amdgcn_s_setprio(0);
    __builtin_amdgcn_s_barrier();
  }

  // ================= epilogue (verified round-2 structure) =================
  // Step 1: ALL waves dump acc into full 256x256 bf16 X tile (exactly 128 KiB). acc dies here.
  int lq = l >> 4, lr = l & 15;
  int t0 = col0 >> 4;                      // first of this block's 16 targets

  float bias[4];
  #pragma unroll
  for (int ni = 0; ni < 4; ++ni) {
    int gcol = col0 + wc * 64 + ni * 16 + lr;
    bias[ni] = (gcol < O_REAL) ? b0[gcol] : 0.f;
  }

  #pragma unroll
  for (int mi = 0; mi < 8; ++mi) {
    #pragma unroll
    for (int ni = 0; ni < 4; ++ni) {
      #pragma unroll
      for (int r = 0; r < 4; ++r) {
        int rowL = wr * 128 + mi * 16 + lq * 4 + r;
        int colL = wc * 64 + ni * 16 + lr;
        int sw = ((rowL ^ (rowL >> 2)) & 7) << 4;
        float v = fmaxf(acc[mi][ni][r] + bias[ni], 0.f);
        *(unsigned short*)(smem + (size_t)rowL * 512 + ((colL * 2) ^ sw)) = f2bf(v);
      }
    }
  }
  __syncthreads();

  // Step 2: wave w owns targets 2w, 2w+1; lanes = rows. W via wave-uniform (scalar) loads.
  int uw = __builtin_amdgcn_readfirstlane(w);
  float oacc[2][4];
  #pragma unroll
  for (int g = 0; g < 2; ++g) {
    int tloc = uw * 2 + g;
    int tt = t0 + tloc;
    bool tvalid = (tt < NTGT);
    const float* w1t = W1g + (size_t)tt * 256;
    float b1v[16], w2v[16];
    float b2v = 0.f;
    if (tvalid) {
      #pragma unroll
      for (int e4 = 0; e4 < 4; ++e4) {
        float4 ba = *(const float4*)(b1g + (size_t)tt * 16 + e4 * 4);
        float4 wa = *(const float4*)(W2g + (size_t)tt * 16 + e4 * 4);
        b1v[e4 * 4 + 0] = ba.x; b1v[e4 * 4 + 1] = ba.y; b1v[e4 * 4 + 2] = ba.z; b1v[e4 * 4 + 3] = ba.w;
        w2v[e4 * 4 + 0] = wa.x; w2v[e4 * 4 + 1] = wa.y; w2v[e4 * 4 + 2] = wa.z; w2v[e4 * 4 + 3] = wa.w;
      }
      b2v = b2g[tt];
    }
    #pragma unroll
    for (int rg = 0; rg < 4; ++rg) {
      int rowL = rg * 64 + l;
      int sw = ((rowL ^ (rowL >> 2)) & 7) << 4;
      const char* bp = smem + (size_t)rowL * 512;
      uint4 va = *(const uint4*)(bp + ((tloc * 32) ^ sw));
      uint4 vb = *(const uint4*)(bp + ((tloc * 32 + 16) ^ sw));
      unsigned q0 = va.x, q1 = va.y, q2 = va.z, q3 = va.w;
      unsigned q4 = vb.x, q5 = vb.y, q6 = vb.z, q7 = vb.w;
      float x[16];
      x[0]  = __uint_as_float(q0 << 16); x[1]  = __uint_as_float(q0 & 0xffff0000u);
      x[2]  = __uint_as_float(q1 << 16); x[3]  = __uint_as_float(q1 & 0xffff0000u);
      x[4]  = __uint_as_float(q2 << 16); x[5]  = __uint_as_float(q2 & 0xffff0000u);
      x[6]  = __uint_as_float(q3 << 16); x[7]  = __uint_as_float(q3 & 0xffff0000u);
      x[8]  = __uint_as_float(q4 << 16); x[9]  = __uint_as_float(q4 & 0xffff0000u);
      x[10] = __uint_as_float(q5 << 16); x[11] = __uint_as_float(q5 & 0xffff0000u);
      x[12] = __uint_as_float(q6 << 16); x[13] = __uint_as_float(q6 & 0xffff0000u);
      x[14] = __uint_as_float(q7 << 16); x[15] = __uint_as_float(q7 & 0xffff0000u);
      float o = 0.f;
      if (tvalid) {
        #pragma unroll
        for (int e = 0; e < 16; ++e) {
          float4 wq0 = *(const float4*)(w1t + e * 16 + 0);
          float4 wq1 = *(const float4*)(w1t + e * 16 + 4);
          float4 wq2 = *(const float4*)(w1t + e * 16 + 8);
          float4 wq3 = *(const float4*)(w1t + e * 16 + 12);
          float s = b1v[e];
          s = fmaf(x[0],  wq0.x, s); s = fmaf(x[1],  wq0.y, s);
          s = fmaf(x[2],  wq0.z, s); s = fmaf(x[3],  wq0.w, s);
          s = fmaf(x[4],  wq1.x, s); s = fmaf(x[5],  wq1.y, s);
          s = fmaf(x[6],  wq1.z, s); s = fmaf(x[7],  wq1.w, s);
          s = fmaf(x[8],  wq2.x, s); s = fmaf(x[9],  wq2.y, s);
          s = fmaf(x[10], wq2.z, s); s = fmaf(x[11], wq2.w, s);
          s = fmaf(x[12], wq3.x, s); s = fmaf(x[13], wq3.y, s);
          s = fmaf(x[14], wq3.z, s); s = fmaf(x[15], wq3.w, s);
          s = fmaxf(s, 0.f);
          o = fmaf(s, w2v[e], o);
        }
        o += b2v;
      }
      oacc[g][rg] = o;
    }
  }
  __syncthreads();   // everyone done reading X

  // Step 3: transpose o through LDS ([256][17] f32 = 17.4 KB over dead X), coalesced out stores
  {
    float* sOut = (float*)smem;
    #pragma unroll
    for (int g = 0; g < 2; ++g) {
      int tloc = uw * 2 + g;
      #pragma unroll
      for (int rg = 0; rg < 4; ++rg)
        sOut[(rg * 64 + l) * 17 + tloc] = oacc[g][rg];
    }
    __syncthreads();
    int c = tid & 15, rr = tid >> 4;
    bool cv = (t0 + c < NTGT);
    #pragma unroll
    for (int j = 0; j < 8; ++j) {
      int row = rr + 32 * j;
      if (cv) out[(size_t)(row0 + row) * NTGT + (t0 + c)] = sOut[row * 17 + c];
    }
  }
#undef STG_A
#undef STG_B
#undef PH_SYNC
#undef PH_END
#undef MFMA_Q
}

extern "C" void kernel_launch(void* const* d_in, const int* in_sizes, int n_in,
                              void* d_out, int out_size, void* d_ws, size_t ws_size,
                              hipStream_t stream) {
  const float* AX = (const float*)d_in[0];
  const float* W0 = (const float*)d_in[1];
  const float* b0 = (const float*)d_in[2];
  const float* W1 = (const float*)d_in[3];
  const float* b1 = (const float*)d_in[4];
  const float* W2 = (const float*)d_in[5];
  const float* b2 = (const float*)d_in[6];
  float* out = (float*)d_out;

  char* ws = (char*)d_ws;
  const size_t szA = (size_t)NROW * KP * 2;     // 20.97 MB
  unsigned short* Ab = (unsigned short*)ws;
  unsigned short* Bb = (unsigned short*)(ws + szA);   // [8192][2560] bf16 = 41.9 MB

  hipFuncSetAttribute((const void*)gemm8, hipFuncAttributeMaxDynamicSharedMemorySize, 131072);

  convAll<<<NBLK_A + NBLK_B + NBLK_P, 256, 0, stream>>>(AX, W0, Ab, Bb);
  gemm8<<<(NROW / 256) * (NPAD / 256), 512, 131072, stream>>>(Ab, Bb, b0, W1, b1, W2, b2, out);
}